// Round 8
// baseline (149.017 us; speedup 1.0000x reference)
//
#include <hip/hip_runtime.h>
#include <hip/hip_fp16.h>

typedef _Float16 h8 __attribute__((ext_vector_type(8)));
typedef _Float16 h4 __attribute__((ext_vector_type(4)));
typedef float fx4 __attribute__((ext_vector_type(4)));

#define NPTS   2048
#define KP1    17
#define PGPT   4          // points per edge-block
#define EDGES  68         // PGPT*17 real edges
#define ROWS   80         // padded to 5 M-tiles
#define MT     5
// static LDS layout for edge kernel (bytes) -- total 52544, x3 -> 3 blocks/CU
// SJ (bias rows u-s+ba1) overlays ATT: SJ live P1->P3, ATT live P4->P5 (post-P3 barrier).
// PH holds ph (P1-P2), ah (P3-P4), then opre f16 [16][128] swzB (P5-P6).
#define DELTA_OFF 0        // f16 [80][128], rowbytes 256, swizzled          (20480)
#define PH_OFF    20480    // f16 [80][64],  rowbytes 128, swizzled (ph->ah) (10240)
#define ATT_OFF   30720    // f16 att_T[128 ch][84 rows], rowbytes 168       (21504)
#define SJ_OFF    30720    // f16 [80][64],  rowbytes 128, swizzled — OVERLAYS ATT
#define NBR_OFF   52224    // int [80]                                         (320)
#define EDGE_SMEM 52544
#define ATT_RB    168

__device__ __forceinline__ int swzA(int row, int bytecol) {  // rowbytes 128
  return (row << 7) + (bytecol ^ ((row & 7) << 4));
}
__device__ __forceinline__ int swzB(int row, int bytecol) {  // rowbytes 256
  return (row << 8) + (bytecol ^ ((row & 7) << 4));
}

// =======================================================================
// A: kNN (2048 blocks, long pole, dispatched first) + h-GEMM (256) +
//    Wall (32) + weight packs (80) — all mutually independent, one dispatch.
// =======================================================================
#define KNN_NB 2048
#define GH_NB  256
#define WP_NB  32
#define PK_NB  80
#define A_GRID (KNN_NB + GH_NB + WP_NB + PK_NB)

__global__ __launch_bounds__(512) void frontA_kernel(
    const float* __restrict__ pos, int* __restrict__ nbr, float* __restrict__ rel,
    const float* __restrict__ x, const float* __restrict__ Wi, const float* __restrict__ bi,
    float* __restrict__ h,
    const float* __restrict__ Wdst, const float* __restrict__ Wsrc,
    const float* __restrict__ Wlin, const float* __restrict__ Wa1,
    float* __restrict__ Wall,
    const float* __restrict__ Wp2, const float* __restrict__ Wa2,
    const float* __restrict__ Wo,
    _Float16* __restrict__ p2p, _Float16* __restrict__ a1p, _Float16* __restrict__ a2p,
    _Float16* __restrict__ wop)
{
  __shared__ __align__(16) char buf[33792];
  const int bid = blockIdx.x;
  const int tid = threadIdx.x;

  if (bid < KNN_NB) {
    // ---------------- kNN v3 + rel; float4 LDS layout {x,y,z,|p|^2} ----------------
    float4* pc = (float4*)buf;                 // [2048]
    int p0 = bid * 8;
    int base = (p0 >> 11) << 11;   // cloud base
    for (int i = tid; i < NPTS; i += 512) {
      float xx = pos[(size_t)(base + i) * 3 + 0];
      float yy = pos[(size_t)(base + i) * 3 + 1];
      float zz = pos[(size_t)(base + i) * 3 + 2];
      float4 v; v.x = xx; v.y = yy; v.z = zz; v.w = xx * xx + yy * yy + zz * zz;
      pc[i] = v;
    }
    __syncthreads();
    int wid = tid >> 6, lane = tid & 63;
    int pl = (p0 & 2047) + wid;
    int gp = base + pl;
    float4 qp = pc[pl];
    float pix = qp.x, piy = qp.y, piz = qp.z;

    // Stage 1: f32 keys dp = (d2 - sqi) + 4 (monotone in d2, >0), packed with t; per-lane top-8
    unsigned key[8];
#pragma unroll
    for (int i = 0; i < 8; ++i) key[i] = 0xFFFFFFFFu;
#pragma unroll
    for (int t = 0; t < 32; ++t) {
      int j = t * 64 + lane;
      float4 c = pc[j];
      float dot = pix * c.x + piy * c.y + piz * c.z;
      float dp = __builtin_fmaf(-2.f, dot, c.w) + 4.0f;
      unsigned kb = (__float_as_uint(dp) & 0xFFFFFFE0u) | (unsigned)t;
      kb = (j == pl) ? 0xFFFFFFFFu : kb;
#pragma unroll
      for (int i = 0; i < 8; ++i) {
        unsigned lo = min(key[i], kb), hi = max(key[i], kb);
        key[i] = lo; kb = hi;
      }
    }

    // Stage 2: exact f64 rerank of the 8 finalists (same formula as reference)
    double pxd = (double)pix, pyd = (double)piy, pzd = (double)piz;
    double sqi64 = pxd * pxd + pyd * pyd + pzd * pzd;
    unsigned long long kk[8];
#pragma unroll
    for (int i = 0; i < 8; ++i) {
      if (key[i] == 0xFFFFFFFFu) { kk[i] = 0xFFFFFFFFFFFFFFFFull; continue; }
      int t = key[i] & 31;
      int j = t * 64 + lane;
      float4 c = pc[j];
      double xj = (double)c.x, yj = (double)c.y, zj = (double)c.z;
      double sqj = xj * xj + yj * yj + zj * zj;
      double dot = pxd * xj + pyd * yj + pzd * zj;
      double d2 = sqi64 + sqj - 2.0 * dot;
      d2 = d2 > 0.0 ? d2 : 0.0;
      unsigned long long bits = (unsigned long long)__double_as_longlong(d2);
      kk[i] = (bits & ~0x7FFull) | (unsigned long long)j;
    }
    // sort kk[0..7] ascending: Batcher 8-element network (19 CEs)
#define CE(a, b) { unsigned long long lo_ = kk[a] < kk[b] ? kk[a] : kk[b]; \
                   unsigned long long hi_ = kk[a] < kk[b] ? kk[b] : kk[a]; \
                   kk[a] = lo_; kk[b] = hi_; }
    CE(0,1) CE(2,3) CE(4,5) CE(6,7)
    CE(0,2) CE(1,3) CE(4,6) CE(5,7)
    CE(1,2) CE(5,6) CE(0,4) CE(3,7)
    CE(1,5) CE(2,6)
    CE(1,4) CE(3,6)
    CE(2,4) CE(3,5)
    CE(3,4)
#undef CE

    // Stage 3: 16 extractions; heads always kk[0]; u32 truncated butterfly + exact fallback
    if (lane == 0) nbr[gp * KP1] = gp;
    if (lane < 3)  rel[(size_t)gp * KP1 * 3 + lane] = 0.f;   // self edge: rel = 0
    for (int it = 0; it < 16; ++it) {
      unsigned h32 = (unsigned)(kk[0] >> 32);
      unsigned key2 = (h32 & ~63u) | (unsigned)lane;
      unsigned m2 = key2;
#pragma unroll
      for (int off = 32; off > 0; off >>= 1) {
        unsigned o = __shfl_xor(m2, off);
        m2 = o < m2 ? o : m2;
      }
      bool same = ((key2 ^ m2) >> 6) == 0;
      unsigned long long ball = __ballot(same);
      int wl; unsigned jwin;
      if (__popcll(ball) == 1) {
        wl = (int)(m2 & 63u);
        unsigned lo32 = (unsigned)kk[0];
        unsigned wlo = __shfl(lo32, wl);
        jwin = wlo & 2047u;
      } else {
        // exact u64 butterfly among the tied truncated class
        unsigned long long mk = same ? kk[0] : 0xFFFFFFFFFFFFFFFFull;
#pragma unroll
        for (int off = 32; off > 0; off >>= 1) {
          unsigned long long o = __shfl_xor(mk, off);
          mk = o < mk ? o : mk;
        }
        jwin = (unsigned)(mk & 2047ull);
        wl = (int)(jwin & 63u);
      }
      if (lane == 0) nbr[gp * KP1 + 1 + it] = base + (int)jwin;
      if (lane < 3) {
        // rel = pos_i - pos_j computed here (positions already staged in LDS)
        float pi = lane == 0 ? pix : (lane == 1 ? piy : piz);
        float pj = ((const float*)&pc[(int)jwin])[lane];
        rel[((size_t)gp * KP1 + 1 + it) * 3 + lane] = pi - pj;
      }
      bool mine = (lane == wl);
#pragma unroll
      for (int i = 0; i < 7; ++i) kk[i] = mine ? kk[i + 1] : kk[i];
      kk[7] = mine ? 0xFFFFFFFFFFFFFFFFull : kk[7];
    }
  } else if (bid < KNN_NB + GH_NB) {
    // ---------------- h = relu(x@Wi + bi), 64x64 tile, 512 threads ----------------
    float* As = (float*)buf;                    // [64][68]
    float* Ws = (float*)(buf + 64 * 68 * 4);    // [64][64]
    long row0 = (long)(bid - KNN_NB) * 64;
    {
      int r = tid >> 3, k8 = (tid & 7) * 8;
      float4 a0 = *(const float4*)(x + (row0 + r) * 64 + k8);
      float4 a1 = *(const float4*)(x + (row0 + r) * 64 + k8 + 4);
      *(float4*)&As[r * 68 + k8] = a0;
      *(float4*)&As[r * 68 + k8 + 4] = a1;
      float4 w0 = *(const float4*)(Wi + r * 64 + k8);
      float4 w1 = *(const float4*)(Wi + r * 64 + k8 + 4);
      *(float4*)&Ws[r * 64 + k8] = w0;
      *(float4*)&Ws[r * 64 + k8 + 4] = w1;
    }
    __syncthreads();
    int tx = tid & 15, ty = tid >> 4;   // ty 0..31
    float acc[2][4] = {};
#pragma unroll 8
    for (int k = 0; k < 64; ++k) {
      float4 w = *(const float4*)&Ws[k * 64 + tx * 4];
      float a0 = As[(ty * 2 + 0) * 68 + k];
      float a1 = As[(ty * 2 + 1) * 68 + k];
      acc[0][0] += a0 * w.x; acc[0][1] += a0 * w.y; acc[0][2] += a0 * w.z; acc[0][3] += a0 * w.w;
      acc[1][0] += a1 * w.x; acc[1][1] += a1 * w.y; acc[1][2] += a1 * w.z; acc[1][3] += a1 * w.w;
    }
    float b0 = bi[tx * 4 + 0], b1 = bi[tx * 4 + 1], b2 = bi[tx * 4 + 2], b3 = bi[tx * 4 + 3];
#pragma unroll
    for (int i = 0; i < 2; ++i) {
      float4 o;
      o.x = fmaxf(acc[i][0] + b0, 0.f); o.y = fmaxf(acc[i][1] + b1, 0.f);
      o.z = fmaxf(acc[i][2] + b2, 0.f); o.w = fmaxf(acc[i][3] + b3, 0.f);
      *(float4*)(h + (row0 + ty * 2 + i) * 64 + tx * 4) = o;
    }
  } else if (bid < KNN_NB + GH_NB + WP_NB) {
    // ---------------- Wall ----------------
    int gid = (bid - KNN_NB - GH_NB) * 512 + tid;   // 0..16383
    int q = gid >> 12, r = (gid >> 6) & 63, c = gid & 63;
    float val;
    if (q < 2) {
      const float* W = q ? Wsrc : Wdst;
      float acc = 0.f;
      for (int k = 0; k < 128; ++k) acc += W[r * 128 + k] * Wa1[k * 64 + c];
      val = acc;
    } else {
      val = Wlin[r * 128 + (q - 2) * 64 + c];
    }
    Wall[r * 256 + q * 64 + c] = val;
  } else {
    // ---------------- packw (consumed only by edge kernel) ----------------
    int gid = (bid - KNN_NB - GH_NB - WP_NB) * 512 + tid;   // 0..40959
    if (gid < 24576) {
      int m = gid >> 13;
      int r = gid & 8191;
      int tl = r >> 9;
      int l  = (r >> 3) & 63;
      int j  = r & 7;
      const float* src; _Float16* dst; int N, kt, nt;
      if (m == 0)      { src = Wp2; dst = p2p; N = 128; kt = tl & 1; nt = tl >> 1; }
      else if (m == 1) { src = Wa1; dst = a1p; N = 64;  kt = tl & 3; nt = tl >> 2; }
      else             { src = Wa2; dst = a2p; N = 128; kt = tl & 1; nt = tl >> 1; }
      int k = kt * 32 + (l >> 4) * 8 + j;
      int n = nt * 16 + (l & 15);
      dst[r] = (_Float16)src[k * N + n];
    } else {
      // Wo [128][128] -> B fragments, kt = tl&3, nt = tl>>2
      int r = gid - 24576;          // 0..16383
      int tl = r >> 9;              // 0..31
      int l  = (r >> 3) & 63;
      int j  = r & 7;
      int kt = tl & 3, nt = tl >> 2;
      int k = kt * 32 + (l >> 4) * 8 + j;
      int n = nt * 16 + (l & 15);
      wop[r] = (_Float16)Wo[k * 128 + n];
    }
  }
}

// =======================================================================
// B: usv = h @ Wall (needs h + Wall from dispatch A). 1024 light blocks.
// =======================================================================
__global__ __launch_bounds__(512) void usv_kernel(
    const float* __restrict__ h, const float* __restrict__ Wall,
    float* __restrict__ usv)
{
  __shared__ __align__(16) char buf[33792];
  const int tid = threadIdx.x;
  float* As = (float*)buf;                    // [64][68]
  float* Ws = (float*)(buf + 64 * 68 * 4);    // [64][64]
  int b2 = blockIdx.x;
  long row0 = (long)(b2 >> 2) * 64;
  int c0 = (b2 & 3) * 64;
  {
    int r = tid >> 3, k8 = (tid & 7) * 8;
    float4 a0 = *(const float4*)(h + (row0 + r) * 64 + k8);
    float4 a1 = *(const float4*)(h + (row0 + r) * 64 + k8 + 4);
    *(float4*)&As[r * 68 + k8] = a0;
    *(float4*)&As[r * 68 + k8 + 4] = a1;
    float4 w0 = *(const float4*)(Wall + r * 256 + c0 + k8);
    float4 w1 = *(const float4*)(Wall + r * 256 + c0 + k8 + 4);
    *(float4*)&Ws[r * 64 + k8] = w0;
    *(float4*)&Ws[r * 64 + k8 + 4] = w1;
  }
  __syncthreads();
  int tx = tid & 15, ty = tid >> 4;   // ty 0..31
  float acc[2][4] = {};
#pragma unroll 8
  for (int k = 0; k < 64; ++k) {
    float4 w = *(const float4*)&Ws[k * 64 + tx * 4];
    float a0 = As[(ty * 2 + 0) * 68 + k];
    float a1 = As[(ty * 2 + 1) * 68 + k];
    acc[0][0] += a0 * w.x; acc[0][1] += a0 * w.y; acc[0][2] += a0 * w.z; acc[0][3] += a0 * w.w;
    acc[1][0] += a1 * w.x; acc[1][1] += a1 * w.y; acc[1][2] += a1 * w.z; acc[1][3] += a1 * w.w;
  }
#pragma unroll
  for (int i = 0; i < 2; ++i) {
    float4 o;
    o.x = acc[i][0]; o.y = acc[i][1]; o.z = acc[i][2]; o.w = acc[i][3];
    *(float4*)(usv + (row0 + ty * 2 + i) * 256 + c0 + tx * 4) = o;
  }
}

// ---------------- fused edge kernel: pos_nn + attn_nn (f16 MFMA) + softmax + mean + lin_out ----------------
__global__ __launch_bounds__(512, 6) void edge_kernel(
    const int* __restrict__ nbr,
    const float* __restrict__ usv,
    const float* __restrict__ rel,
    const float* __restrict__ Wp1, const float* __restrict__ bp1,
    const float* __restrict__ bp2, const float* __restrict__ ba1, const float* __restrict__ ba2,
    const _Float16* __restrict__ Wp2p, const _Float16* __restrict__ Wa1p, const _Float16* __restrict__ Wa2p,
    const _Float16* __restrict__ Wop, const float* __restrict__ bo,
    float* __restrict__ out)
{
  __shared__ __align__(16) char smem[EDGE_SMEM];
  int* nbr_s = (int*)(smem + NBR_OFF);
  const int tid = threadIdx.x;
  const int lane = tid & 63;
  const int wid = tid >> 6;
  // XCD-chunked swizzle: XCD k owns p-blocks [k*512,(k+1)*512) == exactly cloud k
  const int bid = blockIdx.x;
  const int pb = ((bid & 7) << 9) | (bid >> 3);
  const int p0 = pb * PGPT;

  // T14: issue the P5 v-gather NOW; nbr row via wave-uniform global s_loads (SMEM pipe).
  const int pp5 = tid >> 7;            // wave-uniform (wid>>1)
  const int c5 = tid & 127;
  float vreg[KP1];
  {
    const int* __restrict__ nrow = nbr + (size_t)(p0 + pp5) * KP1;
#pragma unroll
    for (int k = 0; k < KP1; ++k) {
      int jv = nrow[k];                            // s_load (wave-uniform)
      vreg[k] = usv[(size_t)jv * 256 + 128 + c5];  // coalesced v-gather
    }
  }

  // P0: stage neighbor list (used by P1's wave-uniform j reads)
  if (tid < ROWS) nbr_s[tid] = (tid < EDGES) ? nbr[p0 * KP1 + tid] : p0;
  __syncthreads();

  // P1: stage bias rows (u_i - s_j + ba1) f16 and compute pos_nn hidden ph (f16), swizzled.
  // rel = pos_i - pos_j precomputed in kNN (identical f32 arithmetic).
  {
    float w1x = Wp1[lane], w1y = Wp1[64 + lane], w1z = Wp1[128 + lane], b1 = bp1[lane];
    float b1a = ba1[lane];
    const float* relb = rel + (size_t)p0 * (KP1 * 3);
    for (int e = wid; e < ROWS; e += 8) {
      int eb = __builtin_amdgcn_readfirstlane(min(e, EDGES - 1));
      int p  = (eb * 241) >> 12;          // eb/17 exact for eb<272
      int j  = __builtin_amdgcn_readfirstlane(nbr_s[eb]);
      float sv = usv[(size_t)j * 256 + 64 + lane];          // coalesced
      float uu = usv[(size_t)(p0 + p) * 256 + lane];        // coalesced, L1-hot
      *(_Float16*)(smem + SJ_OFF + swzA(e, lane * 2)) = (_Float16)(uu - sv + b1a);
      float rx = relb[eb * 3 + 0];
      float ry = relb[eb * 3 + 1];
      float rz = relb[eb * 3 + 2];
      float acc = fmaxf(b1 + rx * w1x + ry * w1y + rz * w1z, 0.f);
      *(_Float16*)(smem + PH_OFF + swzA(e, lane * 2)) = (_Float16)acc;
    }
  }
  __syncthreads();

  const int rl = lane & 15;
  const int kl = lane >> 4;

  // P2: delta = relu(ph @ Wp2 + bp2)  [80 x 128], K=64
  {
    int nt = wid;  // 0..7
    h8 b0 = *(const h8*)(Wp2p + ((size_t)(nt * 2 + 0) * 64 + lane) * 8);
    h8 b1 = *(const h8*)(Wp2p + ((size_t)(nt * 2 + 1) * 64 + lane) * 8);
    int col = nt * 16 + rl;
    float bias2 = bp2[col];
    for (int mt = 0; mt < MT; ++mt) {
      int arow = mt * 16 + rl;
      h8 a0 = *(const h8*)(smem + PH_OFF + swzA(arow, kl * 16));
      h8 a1 = *(const h8*)(smem + PH_OFF + swzA(arow, 64 + kl * 16));
      fx4 acc = {0.f, 0.f, 0.f, 0.f};
      acc = __builtin_amdgcn_mfma_f32_16x16x32_f16(a0, b0, acc, 0, 0, 0);
      acc = __builtin_amdgcn_mfma_f32_16x16x32_f16(a1, b1, acc, 0, 0, 0);
#pragma unroll
      for (int jj = 0; jj < 4; ++jj) {
        int orow = mt * 16 + kl * 4 + jj;
        float val = fmaxf(acc[jj] + bias2, 0.f);
        *(_Float16*)(smem + DELTA_OFF + swzB(orow, col * 2)) = (_Float16)val;
      }
    }
  }
  __syncthreads();

  // P3: t = delta @ Wa1 (K=128); ah = relu(t + bias_row) -> stored in ph space [80x64]
  // bias_row = u_i - s_j + ba1, folded in P1.
  {
    int nt = wid & 3;
    h8 b[4];
#pragma unroll
    for (int kt = 0; kt < 4; ++kt)
      b[kt] = *(const h8*)(Wa1p + ((size_t)(nt * 4 + kt) * 64 + lane) * 8);
    int hcol = nt * 16 + rl;
    for (int mt = (wid >> 2); mt < MT; mt += 2) {
      int arow = mt * 16 + rl;
      fx4 acc = {0.f, 0.f, 0.f, 0.f};
#pragma unroll
      for (int kt = 0; kt < 4; ++kt) {
        h8 a = *(const h8*)(smem + DELTA_OFF + swzB(arow, kt * 64 + kl * 16));
        acc = __builtin_amdgcn_mfma_f32_16x16x32_f16(a, b[kt], acc, 0, 0, 0);
      }
#pragma unroll
      for (int jj = 0; jj < 4; ++jj) {
        int orow = mt * 16 + kl * 4 + jj;
        float bb = (float)*(const _Float16*)(smem + SJ_OFF + swzA(orow, hcol * 2));
        float val = fmaxf(acc[jj] + bb, 0.f);
        *(_Float16*)(smem + PH_OFF + swzA(orow, hcol * 2)) = (_Float16)val;
      }
    }
  }
  __syncthreads();   // <- after this barrier SJ is dead; ATT (same bytes) becomes live

  // P4: attn = relu(ah @ Wa2 + ba2) -> TRANSPOSED att_T[ch][pp*20 + k], guarded to real edges
  {
    int nt = wid;
    h8 b0 = *(const h8*)(Wa2p + ((size_t)(nt * 2 + 0) * 64 + lane) * 8);
    h8 b1 = *(const h8*)(Wa2p + ((size_t)(nt * 2 + 1) * 64 + lane) * 8);
    int col = nt * 16 + rl;
    float b2v = ba2[col];
    char* cbase = smem + ATT_OFF + col * ATT_RB;
    for (int mt = 0; mt < MT; ++mt) {
      int arow = mt * 16 + rl;
      h8 a0 = *(const h8*)(smem + PH_OFF + swzA(arow, kl * 16));
      h8 a1 = *(const h8*)(smem + PH_OFF + swzA(arow, 64 + kl * 16));
      fx4 acc = {0.f, 0.f, 0.f, 0.f};
      acc = __builtin_amdgcn_mfma_f32_16x16x32_f16(a0, b0, acc, 0, 0, 0);
      acc = __builtin_amdgcn_mfma_f32_16x16x32_f16(a1, b1, acc, 0, 0, 0);
#pragma unroll
      for (int jj = 0; jj < 4; ++jj) {
        int orow = mt * 16 + kl * 4 + jj;
        if (orow < EDGES) {
          int pp = (orow * 241) >> 12;
          float val = fmaxf(acc[jj] + b2v, 0.f);
          *(_Float16*)(cbase + (orow + 3 * pp) * 2) = (_Float16)val;  // row_store = pp*20 + k
        }
      }
    }
  }
  __syncthreads();

  // P6 prefetch: Wo B-fragments (consumed after P5; latency hidden by softmax)
  h8 bw[4];
#pragma unroll
  for (int kt = 0; kt < 4; ++kt)
    bw[kt] = *(const h8*)(Wop + ((size_t)(wid * 4 + kt) * 64 + lane) * 8);

  // P5: per-channel softmax over 17 neighbors + weighted mean of (v_j + delta) -> opre f16 in PH
  {
    int r0 = pp5 * KP1;
    const char* abase = smem + ATT_OFF + c5 * ATT_RB + pp5 * 40;
    h4 t0 = *(const h4*)(abase + 0);
    h4 t1 = *(const h4*)(abase + 8);
    h4 t2 = *(const h4*)(abase + 16);
    h4 t3 = *(const h4*)(abase + 24);
    float att[KP1];
#pragma unroll
    for (int q = 0; q < 4; ++q) {
      att[0 + q]  = (float)t0[q];
      att[4 + q]  = (float)t1[q];
      att[8 + q]  = (float)t2[q];
      att[12 + q] = (float)t3[q];
    }
    att[16] = (float)*(const _Float16*)(abase + 32);
    // max tree (short dependency chain; max is exact so any association is identical)
    float m8[8];
#pragma unroll
    for (int k = 0; k < 8; ++k) m8[k] = fmaxf(att[k], att[k + 8]);
    float m4a = fmaxf(m8[0], m8[1]), m4b = fmaxf(m8[2], m8[3]);
    float m4c = fmaxf(m8[4], m8[5]), m4d = fmaxf(m8[6], m8[7]);
    float m = fmaxf(fmaxf(fmaxf(m4a, m4b), fmaxf(m4c, m4d)), att[16]);
    float den = 0.f;
#pragma unroll
    for (int k = 0; k < KP1; ++k) { att[k] = __expf(att[k] - m); den += att[k]; }
    float inv = 1.f / (den * 17.f);
    float acc = 0.f;
#pragma unroll
    for (int k = 0; k < KP1; ++k) {
      float dd = (float)*(const _Float16*)(smem + DELTA_OFF + swzB(r0 + k, c5 * 2));
      acc += att[k] * (vreg[k] + dd);
    }
    // opre row pp5 (0..3), col c5 -> f16 (RTN) into dead PH region, swzB layout
    *(_Float16*)(smem + PH_OFF + swzB(pp5, c5 * 2)) = (_Float16)(acc * inv);
  }
  __syncthreads();

  // P6: out = relu(opre @ Wo + bo). One 16-row M-tile; rows 0..3 real, 4..15 stale-but-finite.
  {
    fx4 acc = {0.f, 0.f, 0.f, 0.f};
#pragma unroll
    for (int kt = 0; kt < 4; ++kt) {
      h8 a = *(const h8*)(smem + PH_OFF + swzB(rl, kt * 64 + kl * 16));
      acc = __builtin_amdgcn_mfma_f32_16x16x32_f16(a, bw[kt], acc, 0, 0, 0);
    }
    if (kl == 0) {               // acc rows 0..3 = the block's 4 points
      int col = wid * 16 + rl;
      float bov = bo[col];
#pragma unroll
      for (int jj = 0; jj < 4; ++jj)
        out[(size_t)(p0 + jj) * 128 + col] = fmaxf(acc[jj] + bov, 0.f);
    }
  }
}

extern "C" void kernel_launch(void* const* d_in, const int* in_sizes, int n_in,
                              void* d_out, int out_size, void* d_ws, size_t ws_size,
                              hipStream_t stream) {
  const float* x    = (const float*)d_in[0];
  const float* pos  = (const float*)d_in[1];
  const float* Wi   = (const float*)d_in[3];
  const float* bi   = (const float*)d_in[4];
  const float* Wsrc = (const float*)d_in[5];
  const float* Wdst = (const float*)d_in[6];
  const float* Wlin = (const float*)d_in[7];
  const float* Wp1  = (const float*)d_in[8];
  const float* bp1  = (const float*)d_in[9];
  const float* Wp2  = (const float*)d_in[10];
  const float* bp2  = (const float*)d_in[11];
  const float* Wa1  = (const float*)d_in[12];
  const float* ba1  = (const float*)d_in[13];
  const float* Wa2  = (const float*)d_in[14];
  const float* ba2  = (const float*)d_in[15];
  const float* Wo   = (const float*)d_in[16];
  const float* bo   = (const float*)d_in[17];
  float* out = (float*)d_out;

  char* ws = (char*)d_ws;
  float* h    = (float*)(ws + 0);          // 16384x64   (4 MB)
  float* usv  = (float*)(ws + 4194304);    // 16384x256  (16 MB): [u|s|v]
  float* Wall = (float*)(ws + 20971520);   // 64x256 (64 KB)
  float* rel  = (float*)(ws + 21037056);   // 16384x17x3 f32 (3.34 MB)
  int*   nbr  = (int*)  (ws + 29360128);   // 16384x17
  _Float16* p2p = (_Float16*)(ws + 30474240);  // 16 KB
  _Float16* a1p = (_Float16*)(ws + 30490624);
  _Float16* a2p = (_Float16*)(ws + 30507008);
  _Float16* wop = (_Float16*)(ws + 30523392);  // 32 KB (Wo packed)

  frontA_kernel<<<A_GRID, 512, 0, stream>>>(pos, nbr, rel, x, Wi, bi, h,
                                            Wdst, Wsrc, Wlin, Wa1, Wall,
                                            Wp2, Wa2, Wo, p2p, a1p, a2p, wop);
  usv_kernel<<<1024, 512, 0, stream>>>(h, Wall, usv);
  edge_kernel<<<4096, 512, 0, stream>>>(nbr, usv, rel, Wp1, bp1, bp2, ba1, ba2,
                                        p2p, a1p, a2p, wop, bo, out);
}

// Round 9
// 133.172 us; speedup vs baseline: 1.1190x; 1.1190x over previous
//
#include <hip/hip_runtime.h>
#include <hip/hip_fp16.h>

typedef _Float16 h8 __attribute__((ext_vector_type(8)));
typedef _Float16 h4 __attribute__((ext_vector_type(4)));
typedef float fx4 __attribute__((ext_vector_type(4)));

#define NPTS   2048
#define KP1    17
#define PGPT   4          // points per edge-block
#define EDGES  68         // PGPT*17 real edges
#define ROWS   80         // padded to 5 M-tiles
#define MT     5
// static LDS layout for edge kernel (bytes) -- total 52544, x3 -> 3 blocks/CU
// SJ (bias rows u-s+ba1) overlays ATT: SJ live P1->P3, ATT live P4->P5 (post-P3 barrier).
// PH holds ph (P1-P2), ah (P3-P4), then opre f16 [16][128] swzB (P5-P6).
#define DELTA_OFF 0        // f16 [80][128], rowbytes 256, swizzled          (20480)
#define PH_OFF    20480    // f16 [80][64],  rowbytes 128, swizzled (ph->ah) (10240)
#define ATT_OFF   30720    // f16 att_T[128 ch][84 rows], rowbytes 168       (21504)
#define SJ_OFF    30720    // f16 [80][64],  rowbytes 128, swizzled — OVERLAYS ATT
#define NBR_OFF   52224    // int [80]                                         (320)
#define EDGE_SMEM 52544
#define ATT_RB    168

__device__ __forceinline__ int swzA(int row, int bytecol) {  // rowbytes 128
  return (row << 7) + (bytecol ^ ((row & 7) << 4));
}
__device__ __forceinline__ int swzB(int row, int bytecol) {  // rowbytes 256
  return (row << 8) + (bytecol ^ ((row & 7) << 4));
}

// =======================================================================
// K1: minimal serial prefix — ONLY what K2's usv-GEMM needs.
//   blocks [0,256)    : h = relu(x@Wi + bi)   (512-thread 64x64 GEMM)
//   blocks [256,288)  : Wall = [Wdst@Wa1 | Wsrc@Wa1 | Wlin]
// =======================================================================
#define GH_NB    256
#define WP_NB    32
#define P1_GRID  (GH_NB + WP_NB)

__global__ __launch_bounds__(512) void phase1_kernel(
    const float* __restrict__ x, const float* __restrict__ Wi, const float* __restrict__ bi,
    float* __restrict__ h,
    const float* __restrict__ Wdst, const float* __restrict__ Wsrc,
    const float* __restrict__ Wlin, const float* __restrict__ Wa1,
    float* __restrict__ Wall)
{
  __shared__ __align__(16) char buf[33792];
  const int bid = blockIdx.x;
  const int tid = threadIdx.x;

  if (bid < GH_NB) {
    // ---------------- h = relu(x@Wi + bi), 64x64 tile, 512 threads ----------------
    float* As = (float*)buf;                    // [64][68]
    float* Ws = (float*)(buf + 64 * 68 * 4);    // [64][64]
    long row0 = (long)bid * 64;
    {
      int r = tid >> 3, k8 = (tid & 7) * 8;
      float4 a0 = *(const float4*)(x + (row0 + r) * 64 + k8);
      float4 a1 = *(const float4*)(x + (row0 + r) * 64 + k8 + 4);
      *(float4*)&As[r * 68 + k8] = a0;
      *(float4*)&As[r * 68 + k8 + 4] = a1;
      float4 w0 = *(const float4*)(Wi + r * 64 + k8);
      float4 w1 = *(const float4*)(Wi + r * 64 + k8 + 4);
      *(float4*)&Ws[r * 64 + k8] = w0;
      *(float4*)&Ws[r * 64 + k8 + 4] = w1;
    }
    __syncthreads();
    int tx = tid & 15, ty = tid >> 4;   // ty 0..31
    float acc[2][4] = {};
#pragma unroll 8
    for (int k = 0; k < 64; ++k) {
      float4 w = *(const float4*)&Ws[k * 64 + tx * 4];
      float a0 = As[(ty * 2 + 0) * 68 + k];
      float a1 = As[(ty * 2 + 1) * 68 + k];
      acc[0][0] += a0 * w.x; acc[0][1] += a0 * w.y; acc[0][2] += a0 * w.z; acc[0][3] += a0 * w.w;
      acc[1][0] += a1 * w.x; acc[1][1] += a1 * w.y; acc[1][2] += a1 * w.z; acc[1][3] += a1 * w.w;
    }
    float b0 = bi[tx * 4 + 0], b1 = bi[tx * 4 + 1], b2 = bi[tx * 4 + 2], b3 = bi[tx * 4 + 3];
#pragma unroll
    for (int i = 0; i < 2; ++i) {
      float4 o;
      o.x = fmaxf(acc[i][0] + b0, 0.f); o.y = fmaxf(acc[i][1] + b1, 0.f);
      o.z = fmaxf(acc[i][2] + b2, 0.f); o.w = fmaxf(acc[i][3] + b3, 0.f);
      *(float4*)(h + (row0 + ty * 2 + i) * 64 + tx * 4) = o;
    }
  } else {
    // ---------------- Wall ----------------
    int gid = (bid - GH_NB) * 512 + tid;   // 0..16383
    int q = gid >> 12, r = (gid >> 6) & 63, c = gid & 63;
    float val;
    if (q < 2) {
      const float* W = q ? Wsrc : Wdst;
      float acc = 0.f;
      for (int k = 0; k < 128; ++k) acc += W[r * 128 + k] * Wa1[k * 64 + c];
      val = acc;
    } else {
      val = Wlin[r * 128 + (q - 2) * 64 + c];
    }
    Wall[r * 256 + q * 64 + c] = val;
  }
}

// =======================================================================
// K2: kNN (1024 blocks, 2 queries/wave, scalar SoA LDS — conflict-free)
//     + usv = h @ Wall (1024) + weight packs (80) in the kNN shadow.
// =======================================================================
#define KNN_NB 1024
#define UG_NB  1024
#define PK_NB  80
#define K2_GRID (KNN_NB + UG_NB + PK_NB)

__global__ __launch_bounds__(512) void knn_usv_kernel(
    const float* __restrict__ pos, int* __restrict__ nbr, float* __restrict__ rel,
    const float* __restrict__ h, const float* __restrict__ Wall,
    float* __restrict__ usv,
    const float* __restrict__ Wp2, const float* __restrict__ Wa1,
    const float* __restrict__ Wa2, const float* __restrict__ Wo,
    _Float16* __restrict__ p2p, _Float16* __restrict__ a1p, _Float16* __restrict__ a2p,
    _Float16* __restrict__ wop)
{
  __shared__ __align__(16) char buf[33792];
  const int bid = blockIdx.x;
  const int tid = threadIdx.x;

  if (bid < KNN_NB) {
    // ---------------- kNN: 16 points/block, 2 queries/wave, scalar SoA ----------------
    float* px  = (float*)buf;
    float* py  = (float*)(buf + 8192);
    float* pz  = (float*)(buf + 16384);
    float* sqs = (float*)(buf + 24576);
    int p0 = bid * 16;
    int base = (p0 >> 11) << 11;   // cloud base (128 blocks/cloud)
    for (int i = tid; i < NPTS; i += 512) {
      float xx = pos[(size_t)(base + i) * 3 + 0];
      float yy = pos[(size_t)(base + i) * 3 + 1];
      float zz = pos[(size_t)(base + i) * 3 + 2];
      px[i] = xx; py[i] = yy; pz[i] = zz;
      sqs[i] = xx * xx + yy * yy + zz * zz;
    }
    __syncthreads();
    int wid = tid >> 6, lane = tid & 63;
    int pl0 = (p0 & 2047) + wid * 2;
    int pl1 = pl0 + 1;
    float pix0 = px[pl0], piy0 = py[pl0], piz0 = pz[pl0];
    float pix1 = px[pl1], piy1 = py[pl1], piz1 = pz[pl1];

    // Stage 1: shared candidate loads; two independent per-lane top-8 streams.
    // Keys dp = (d2 - sqi) + 4 (monotone in d2, >0), packed with t.
    unsigned key0[8], key1[8];
#pragma unroll
    for (int i = 0; i < 8; ++i) { key0[i] = 0xFFFFFFFFu; key1[i] = 0xFFFFFFFFu; }
#pragma unroll
    for (int t = 0; t < 32; ++t) {
      int j = t * 64 + lane;
      float xx = px[j], yy = py[j], zz = pz[j], sq = sqs[j];   // 4 LDS, shared by both queries
      {
        float dot = pix0 * xx + piy0 * yy + piz0 * zz;
        float dp = __builtin_fmaf(-2.f, dot, sq) + 4.0f;
        unsigned kb = (__float_as_uint(dp) & 0xFFFFFFE0u) | (unsigned)t;
        kb = (j == pl0) ? 0xFFFFFFFFu : kb;
#pragma unroll
        for (int i = 0; i < 8; ++i) {
          unsigned lo = min(key0[i], kb), hi = max(key0[i], kb);
          key0[i] = lo; kb = hi;
        }
      }
      {
        float dot = pix1 * xx + piy1 * yy + piz1 * zz;
        float dp = __builtin_fmaf(-2.f, dot, sq) + 4.0f;
        unsigned kb = (__float_as_uint(dp) & 0xFFFFFFE0u) | (unsigned)t;
        kb = (j == pl1) ? 0xFFFFFFFFu : kb;
#pragma unroll
        for (int i = 0; i < 8; ++i) {
          unsigned lo = min(key1[i], kb), hi = max(key1[i], kb);
          key1[i] = lo; kb = hi;
        }
      }
    }

#pragma unroll 1
    for (int q = 0; q < 2; ++q) {
      int pl = q ? pl1 : pl0;
      int gp = base + pl;
      float pix = q ? pix1 : pix0, piy = q ? piy1 : piy0, piz = q ? piz1 : piz0;

      // Stage 2: exact f64 rerank of the 8 finalists (same formula as reference)
      double pxd = (double)pix, pyd = (double)piy, pzd = (double)piz;
      double sqi64 = pxd * pxd + pyd * pyd + pzd * pzd;
      unsigned long long kk[8];
#pragma unroll
      for (int i = 0; i < 8; ++i) {
        unsigned ky = q ? key1[i] : key0[i];
        if (ky == 0xFFFFFFFFu) { kk[i] = 0xFFFFFFFFFFFFFFFFull; continue; }
        int t = ky & 31;
        int j = t * 64 + lane;
        double xj = (double)px[j], yj = (double)py[j], zj = (double)pz[j];
        double sqj = xj * xj + yj * yj + zj * zj;
        double dot = pxd * xj + pyd * yj + pzd * zj;
        double d2 = sqi64 + sqj - 2.0 * dot;
        d2 = d2 > 0.0 ? d2 : 0.0;
        unsigned long long bits = (unsigned long long)__double_as_longlong(d2);
        kk[i] = (bits & ~0x7FFull) | (unsigned long long)j;
      }
      // sort kk[0..7] ascending: Batcher 8-element network (19 CEs)
#define CE(a, b) { unsigned long long lo_ = kk[a] < kk[b] ? kk[a] : kk[b]; \
                   unsigned long long hi_ = kk[a] < kk[b] ? kk[b] : kk[a]; \
                   kk[a] = lo_; kk[b] = hi_; }
      CE(0,1) CE(2,3) CE(4,5) CE(6,7)
      CE(0,2) CE(1,3) CE(4,6) CE(5,7)
      CE(1,2) CE(5,6) CE(0,4) CE(3,7)
      CE(1,5) CE(2,6)
      CE(1,4) CE(3,6)
      CE(2,4) CE(3,5)
      CE(3,4)
#undef CE

      // Stage 3: 16 extractions; heads always kk[0]; u32 truncated butterfly + exact fallback
      if (lane == 0) nbr[gp * KP1] = gp;
      if (lane < 3)  rel[(size_t)gp * KP1 * 3 + lane] = 0.f;   // self edge: rel = 0
      for (int it = 0; it < 16; ++it) {
        unsigned h32 = (unsigned)(kk[0] >> 32);
        unsigned key2 = (h32 & ~63u) | (unsigned)lane;
        unsigned m2 = key2;
#pragma unroll
        for (int off = 32; off > 0; off >>= 1) {
          unsigned o = __shfl_xor(m2, off);
          m2 = o < m2 ? o : m2;
        }
        bool same = ((key2 ^ m2) >> 6) == 0;
        unsigned long long ball = __ballot(same);
        int wl; unsigned jwin;
        if (__popcll(ball) == 1) {
          wl = (int)(m2 & 63u);
          unsigned lo32 = (unsigned)kk[0];
          unsigned wlo = __shfl(lo32, wl);
          jwin = wlo & 2047u;
        } else {
          // exact u64 butterfly among the tied truncated class
          unsigned long long mk = same ? kk[0] : 0xFFFFFFFFFFFFFFFFull;
#pragma unroll
          for (int off = 32; off > 0; off >>= 1) {
            unsigned long long o = __shfl_xor(mk, off);
            mk = o < mk ? o : mk;
          }
          jwin = (unsigned)(mk & 2047ull);
          wl = (int)(jwin & 63u);
        }
        if (lane == 0) nbr[gp * KP1 + 1 + it] = base + (int)jwin;
        if (lane < 3) {
          // rel = pos_i - pos_j computed here (positions already staged in LDS)
          const float* ps = lane == 0 ? px : (lane == 1 ? py : pz);
          float pi = lane == 0 ? pix : (lane == 1 ? piy : piz);
          rel[((size_t)gp * KP1 + 1 + it) * 3 + lane] = pi - ps[(int)jwin];
        }
        bool mine = (lane == wl);
#pragma unroll
        for (int i = 0; i < 7; ++i) kk[i] = mine ? kk[i + 1] : kk[i];
        kk[7] = mine ? 0xFFFFFFFFFFFFFFFFull : kk[7];
      }
    }
  } else if (bid < KNN_NB + UG_NB) {
    // ---------------- usv = h @ Wall, 64x64 tile, 512 threads ----------------
    float* As = (float*)buf;                    // [64][68]
    float* Ws = (float*)(buf + 64 * 68 * 4);    // [64][64]
    int b2 = bid - KNN_NB;
    long row0 = (long)(b2 >> 2) * 64;
    int c0 = (b2 & 3) * 64;
    {
      int r = tid >> 3, k8 = (tid & 7) * 8;
      float4 a0 = *(const float4*)(h + (row0 + r) * 64 + k8);
      float4 a1 = *(const float4*)(h + (row0 + r) * 64 + k8 + 4);
      *(float4*)&As[r * 68 + k8] = a0;
      *(float4*)&As[r * 68 + k8 + 4] = a1;
      float4 w0 = *(const float4*)(Wall + r * 256 + c0 + k8);
      float4 w1 = *(const float4*)(Wall + r * 256 + c0 + k8 + 4);
      *(float4*)&Ws[r * 64 + k8] = w0;
      *(float4*)&Ws[r * 64 + k8 + 4] = w1;
    }
    __syncthreads();
    int tx = tid & 15, ty = tid >> 4;   // ty 0..31
    float acc[2][4] = {};
#pragma unroll 8
    for (int k = 0; k < 64; ++k) {
      float4 w = *(const float4*)&Ws[k * 64 + tx * 4];
      float a0 = As[(ty * 2 + 0) * 68 + k];
      float a1 = As[(ty * 2 + 1) * 68 + k];
      acc[0][0] += a0 * w.x; acc[0][1] += a0 * w.y; acc[0][2] += a0 * w.z; acc[0][3] += a0 * w.w;
      acc[1][0] += a1 * w.x; acc[1][1] += a1 * w.y; acc[1][2] += a1 * w.z; acc[1][3] += a1 * w.w;
    }
#pragma unroll
    for (int i = 0; i < 2; ++i) {
      float4 o;
      o.x = acc[i][0]; o.y = acc[i][1]; o.z = acc[i][2]; o.w = acc[i][3];
      *(float4*)(usv + (row0 + ty * 2 + i) * 256 + c0 + tx * 4) = o;
    }
  } else {
    // ---------------- packw (consumed only by edge kernel) ----------------
    int gid = (bid - KNN_NB - UG_NB) * 512 + tid;   // 0..40959
    if (gid < 24576) {
      int m = gid >> 13;
      int r = gid & 8191;
      int tl = r >> 9;
      int l  = (r >> 3) & 63;
      int j  = r & 7;
      const float* src; _Float16* dst; int N, kt, nt;
      if (m == 0)      { src = Wp2; dst = p2p; N = 128; kt = tl & 1; nt = tl >> 1; }
      else if (m == 1) { src = Wa1; dst = a1p; N = 64;  kt = tl & 3; nt = tl >> 2; }
      else             { src = Wa2; dst = a2p; N = 128; kt = tl & 1; nt = tl >> 1; }
      int k = kt * 32 + (l >> 4) * 8 + j;
      int n = nt * 16 + (l & 15);
      dst[r] = (_Float16)src[k * N + n];
    } else {
      // Wo [128][128] -> B fragments, kt = tl&3, nt = tl>>2
      int r = gid - 24576;          // 0..16383
      int tl = r >> 9;              // 0..31
      int l  = (r >> 3) & 63;
      int j  = r & 7;
      int kt = tl & 3, nt = tl >> 2;
      int k = kt * 32 + (l >> 4) * 8 + j;
      int n = nt * 16 + (l & 15);
      wop[r] = (_Float16)Wo[k * 128 + n];
    }
  }
}

// ---------------- fused edge kernel: pos_nn + attn_nn (f16 MFMA) + softmax + mean + lin_out ----------------
__global__ __launch_bounds__(512, 6) void edge_kernel(
    const int* __restrict__ nbr,
    const float* __restrict__ usv,
    const float* __restrict__ rel,
    const float* __restrict__ Wp1, const float* __restrict__ bp1,
    const float* __restrict__ bp2, const float* __restrict__ ba1, const float* __restrict__ ba2,
    const _Float16* __restrict__ Wp2p, const _Float16* __restrict__ Wa1p, const _Float16* __restrict__ Wa2p,
    const _Float16* __restrict__ Wop, const float* __restrict__ bo,
    float* __restrict__ out)
{
  __shared__ __align__(16) char smem[EDGE_SMEM];
  int* nbr_s = (int*)(smem + NBR_OFF);
  const int tid = threadIdx.x;
  const int lane = tid & 63;
  const int wid = tid >> 6;
  // XCD-chunked swizzle: XCD k owns p-blocks [k*512,(k+1)*512) == exactly cloud k
  const int bid = blockIdx.x;
  const int pb = ((bid & 7) << 9) | (bid >> 3);
  const int p0 = pb * PGPT;

  // T14: issue the P5 v-gather NOW; nbr row via wave-uniform global s_loads (SMEM pipe).
  const int pp5 = tid >> 7;            // wave-uniform (wid>>1)
  const int c5 = tid & 127;
  float vreg[KP1];
  {
    const int* __restrict__ nrow = nbr + (size_t)(p0 + pp5) * KP1;
#pragma unroll
    for (int k = 0; k < KP1; ++k) {
      int jv = nrow[k];                            // s_load (wave-uniform)
      vreg[k] = usv[(size_t)jv * 256 + 128 + c5];  // coalesced v-gather
    }
  }

  // P0: stage neighbor list (used by P1's wave-uniform j reads)
  if (tid < ROWS) nbr_s[tid] = (tid < EDGES) ? nbr[p0 * KP1 + tid] : p0;
  __syncthreads();

  // P1: stage bias rows (u_i - s_j + ba1) f16 and compute pos_nn hidden ph (f16), swizzled.
  // rel = pos_i - pos_j precomputed in kNN (identical f32 arithmetic).
  {
    float w1x = Wp1[lane], w1y = Wp1[64 + lane], w1z = Wp1[128 + lane], b1 = bp1[lane];
    float b1a = ba1[lane];
    const float* relb = rel + (size_t)p0 * (KP1 * 3);
    for (int e = wid; e < ROWS; e += 8) {
      int eb = __builtin_amdgcn_readfirstlane(min(e, EDGES - 1));
      int p  = (eb * 241) >> 12;          // eb/17 exact for eb<272
      int j  = __builtin_amdgcn_readfirstlane(nbr_s[eb]);
      float sv = usv[(size_t)j * 256 + 64 + lane];          // coalesced
      float uu = usv[(size_t)(p0 + p) * 256 + lane];        // coalesced, L1-hot
      *(_Float16*)(smem + SJ_OFF + swzA(e, lane * 2)) = (_Float16)(uu - sv + b1a);
      float rx = relb[eb * 3 + 0];
      float ry = relb[eb * 3 + 1];
      float rz = relb[eb * 3 + 2];
      float acc = fmaxf(b1 + rx * w1x + ry * w1y + rz * w1z, 0.f);
      *(_Float16*)(smem + PH_OFF + swzA(e, lane * 2)) = (_Float16)acc;
    }
  }
  __syncthreads();

  const int rl = lane & 15;
  const int kl = lane >> 4;

  // P2: delta = relu(ph @ Wp2 + bp2)  [80 x 128], K=64
  {
    int nt = wid;  // 0..7
    h8 b0 = *(const h8*)(Wp2p + ((size_t)(nt * 2 + 0) * 64 + lane) * 8);
    h8 b1 = *(const h8*)(Wp2p + ((size_t)(nt * 2 + 1) * 64 + lane) * 8);
    int col = nt * 16 + rl;
    float bias2 = bp2[col];
    for (int mt = 0; mt < MT; ++mt) {
      int arow = mt * 16 + rl;
      h8 a0 = *(const h8*)(smem + PH_OFF + swzA(arow, kl * 16));
      h8 a1 = *(const h8*)(smem + PH_OFF + swzA(arow, 64 + kl * 16));
      fx4 acc = {0.f, 0.f, 0.f, 0.f};
      acc = __builtin_amdgcn_mfma_f32_16x16x32_f16(a0, b0, acc, 0, 0, 0);
      acc = __builtin_amdgcn_mfma_f32_16x16x32_f16(a1, b1, acc, 0, 0, 0);
#pragma unroll
      for (int jj = 0; jj < 4; ++jj) {
        int orow = mt * 16 + kl * 4 + jj;
        float val = fmaxf(acc[jj] + bias2, 0.f);
        *(_Float16*)(smem + DELTA_OFF + swzB(orow, col * 2)) = (_Float16)val;
      }
    }
  }
  __syncthreads();

  // P3: t = delta @ Wa1 (K=128); ah = relu(t + bias_row) -> stored in ph space [80x64]
  // bias_row = u_i - s_j + ba1, folded in P1.
  {
    int nt = wid & 3;
    h8 b[4];
#pragma unroll
    for (int kt = 0; kt < 4; ++kt)
      b[kt] = *(const h8*)(Wa1p + ((size_t)(nt * 4 + kt) * 64 + lane) * 8);
    int hcol = nt * 16 + rl;
    for (int mt = (wid >> 2); mt < MT; mt += 2) {
      int arow = mt * 16 + rl;
      fx4 acc = {0.f, 0.f, 0.f, 0.f};
#pragma unroll
      for (int kt = 0; kt < 4; ++kt) {
        h8 a = *(const h8*)(smem + DELTA_OFF + swzB(arow, kt * 64 + kl * 16));
        acc = __builtin_amdgcn_mfma_f32_16x16x32_f16(a, b[kt], acc, 0, 0, 0);
      }
#pragma unroll
      for (int jj = 0; jj < 4; ++jj) {
        int orow = mt * 16 + kl * 4 + jj;
        float bb = (float)*(const _Float16*)(smem + SJ_OFF + swzA(orow, hcol * 2));
        float val = fmaxf(acc[jj] + bb, 0.f);
        *(_Float16*)(smem + PH_OFF + swzA(orow, hcol * 2)) = (_Float16)val;
      }
    }
  }
  __syncthreads();   // <- after this barrier SJ is dead; ATT (same bytes) becomes live

  // P4: attn = relu(ah @ Wa2 + ba2) -> TRANSPOSED att_T[ch][pp*20 + k], guarded to real edges
  {
    int nt = wid;
    h8 b0 = *(const h8*)(Wa2p + ((size_t)(nt * 2 + 0) * 64 + lane) * 8);
    h8 b1 = *(const h8*)(Wa2p + ((size_t)(nt * 2 + 1) * 64 + lane) * 8);
    int col = nt * 16 + rl;
    float b2v = ba2[col];
    char* cbase = smem + ATT_OFF + col * ATT_RB;
    for (int mt = 0; mt < MT; ++mt) {
      int arow = mt * 16 + rl;
      h8 a0 = *(const h8*)(smem + PH_OFF + swzA(arow, kl * 16));
      h8 a1 = *(const h8*)(smem + PH_OFF + swzA(arow, 64 + kl * 16));
      fx4 acc = {0.f, 0.f, 0.f, 0.f};
      acc = __builtin_amdgcn_mfma_f32_16x16x32_f16(a0, b0, acc, 0, 0, 0);
      acc = __builtin_amdgcn_mfma_f32_16x16x32_f16(a1, b1, acc, 0, 0, 0);
#pragma unroll
      for (int jj = 0; jj < 4; ++jj) {
        int orow = mt * 16 + kl * 4 + jj;
        if (orow < EDGES) {
          int pp = (orow * 241) >> 12;
          float val = fmaxf(acc[jj] + b2v, 0.f);
          *(_Float16*)(cbase + (orow + 3 * pp) * 2) = (_Float16)val;  // row_store = pp*20 + k
        }
      }
    }
  }
  __syncthreads();

  // P6 prefetch: Wo B-fragments (consumed after P5; latency hidden by softmax)
  h8 bw[4];
#pragma unroll
  for (int kt = 0; kt < 4; ++kt)
    bw[kt] = *(const h8*)(Wop + ((size_t)(wid * 4 + kt) * 64 + lane) * 8);

  // P5: per-channel softmax over 17 neighbors + weighted mean of (v_j + delta) -> opre f16 in PH
  {
    int r0 = pp5 * KP1;
    const char* abase = smem + ATT_OFF + c5 * ATT_RB + pp5 * 40;
    h4 t0 = *(const h4*)(abase + 0);
    h4 t1 = *(const h4*)(abase + 8);
    h4 t2 = *(const h4*)(abase + 16);
    h4 t3 = *(const h4*)(abase + 24);
    float att[KP1];
#pragma unroll
    for (int q = 0; q < 4; ++q) {
      att[0 + q]  = (float)t0[q];
      att[4 + q]  = (float)t1[q];
      att[8 + q]  = (float)t2[q];
      att[12 + q] = (float)t3[q];
    }
    att[16] = (float)*(const _Float16*)(abase + 32);
    // max tree (short dependency chain; max is exact so any association is identical)
    float m8[8];
#pragma unroll
    for (int k = 0; k < 8; ++k) m8[k] = fmaxf(att[k], att[k + 8]);
    float m4a = fmaxf(m8[0], m8[1]), m4b = fmaxf(m8[2], m8[3]);
    float m4c = fmaxf(m8[4], m8[5]), m4d = fmaxf(m8[6], m8[7]);
    float m = fmaxf(fmaxf(fmaxf(m4a, m4b), fmaxf(m4c, m4d)), att[16]);
    float den = 0.f;
#pragma unroll
    for (int k = 0; k < KP1; ++k) { att[k] = __expf(att[k] - m); den += att[k]; }
    float inv = 1.f / (den * 17.f);
    float acc = 0.f;
#pragma unroll
    for (int k = 0; k < KP1; ++k) {
      float dd = (float)*(const _Float16*)(smem + DELTA_OFF + swzB(r0 + k, c5 * 2));
      acc += att[k] * (vreg[k] + dd);
    }
    // opre row pp5 (0..3), col c5 -> f16 (RTN) into dead PH region, swzB layout
    *(_Float16*)(smem + PH_OFF + swzB(pp5, c5 * 2)) = (_Float16)(acc * inv);
  }
  __syncthreads();

  // P6: out = relu(opre @ Wo + bo). One 16-row M-tile; rows 0..3 real, 4..15 stale-but-finite.
  {
    fx4 acc = {0.f, 0.f, 0.f, 0.f};
#pragma unroll
    for (int kt = 0; kt < 4; ++kt) {
      h8 a = *(const h8*)(smem + PH_OFF + swzB(rl, kt * 64 + kl * 16));
      acc = __builtin_amdgcn_mfma_f32_16x16x32_f16(a, bw[kt], acc, 0, 0, 0);
    }
    if (kl == 0) {               // acc rows 0..3 = the block's 4 points
      int col = wid * 16 + rl;
      float bov = bo[col];
#pragma unroll
      for (int jj = 0; jj < 4; ++jj)
        out[(size_t)(p0 + jj) * 128 + col] = fmaxf(acc[jj] + bov, 0.f);
    }
  }
}

extern "C" void kernel_launch(void* const* d_in, const int* in_sizes, int n_in,
                              void* d_out, int out_size, void* d_ws, size_t ws_size,
                              hipStream_t stream) {
  const float* x    = (const float*)d_in[0];
  const float* pos  = (const float*)d_in[1];
  const float* Wi   = (const float*)d_in[3];
  const float* bi   = (const float*)d_in[4];
  const float* Wsrc = (const float*)d_in[5];
  const float* Wdst = (const float*)d_in[6];
  const float* Wlin = (const float*)d_in[7];
  const float* Wp1  = (const float*)d_in[8];
  const float* bp1  = (const float*)d_in[9];
  const float* Wp2  = (const float*)d_in[10];
  const float* bp2  = (const float*)d_in[11];
  const float* Wa1  = (const float*)d_in[12];
  const float* ba1  = (const float*)d_in[13];
  const float* Wa2  = (const float*)d_in[14];
  const float* ba2  = (const float*)d_in[15];
  const float* Wo   = (const float*)d_in[16];
  const float* bo   = (const float*)d_in[17];
  float* out = (float*)d_out;

  char* ws = (char*)d_ws;
  float* h    = (float*)(ws + 0);          // 16384x64   (4 MB)
  float* usv  = (float*)(ws + 4194304);    // 16384x256  (16 MB): [u|s|v]
  float* Wall = (float*)(ws + 20971520);   // 64x256 (64 KB)
  float* rel  = (float*)(ws + 21037056);   // 16384x17x3 f32 (3.34 MB)
  int*   nbr  = (int*)  (ws + 29360128);   // 16384x17
  _Float16* p2p = (_Float16*)(ws + 30474240);  // 16 KB
  _Float16* a1p = (_Float16*)(ws + 30490624);
  _Float16* a2p = (_Float16*)(ws + 30507008);
  _Float16* wop = (_Float16*)(ws + 30523392);  // 32 KB (Wo packed)

  phase1_kernel<<<P1_GRID, 512, 0, stream>>>(x, Wi, bi, h, Wdst, Wsrc, Wlin, Wa1, Wall);
  knn_usv_kernel<<<K2_GRID, 512, 0, stream>>>(pos, nbr, rel, h, Wall, usv,
                                              Wp2, Wa1, Wa2, Wo, p2p, a1p, a2p, wop);
  edge_kernel<<<4096, 512, 0, stream>>>(nbr, usv, rel, Wp1, bp1, bp2, ba1, ba2,
                                        p2p, a1p, a2p, wop, bo, out);
}

// Round 10
// 127.586 us; speedup vs baseline: 1.1680x; 1.0438x over previous
//
#include <hip/hip_runtime.h>
#include <hip/hip_fp16.h>

typedef _Float16 h8 __attribute__((ext_vector_type(8)));
typedef _Float16 h4 __attribute__((ext_vector_type(4)));
typedef float fx4 __attribute__((ext_vector_type(4)));

#define NPTS   2048
#define KP1    17
#define PGPT   4          // points per edge-block
#define EDGES  68         // PGPT*17 real edges
#define ROWS   80         // padded to 5 M-tiles
#define MT     5
// static LDS layout for edge kernel (bytes) -- total 52544, x3 -> 3 blocks/CU
// SJ (bias rows u-s+ba1) overlays ATT: SJ live P1->P3, ATT live P4->P5 (post-P3 barrier).
// PH holds ph (P1-P2), ah (P3-P4), then opre f16 [16][128] swzB (P5-P6).
#define DELTA_OFF 0        // f16 [80][128], rowbytes 256, swizzled          (20480)
#define PH_OFF    20480    // f16 [80][64],  rowbytes 128, swizzled (ph->ah) (10240)
#define ATT_OFF   30720    // f16 att_T[128 ch][84 rows], rowbytes 168       (21504)
#define SJ_OFF    30720    // f16 [80][64],  rowbytes 128, swizzled — OVERLAYS ATT
#define NBR_OFF   52224    // int [80]                                         (320)
#define EDGE_SMEM 52544
#define ATT_RB    168

__device__ __forceinline__ int swzA(int row, int bytecol) {  // rowbytes 128
  return (row << 7) + (bytecol ^ ((row & 7) << 4));
}
__device__ __forceinline__ int swzB(int row, int bytecol) {  // rowbytes 256
  return (row << 8) + (bytecol ^ ((row & 7) << 4));
}

// =======================================================================
// K1: minimal serial prefix — h = relu(x@Wi+bi) with Wall folded into the
// same 256 blocks (64 Wall entries each, 8 lanes/entry), so K1 is exactly
// 1 block/CU and its duration is a single block's time.
// =======================================================================
#define GH_NB    256
#define P1_GRID  GH_NB

__global__ __launch_bounds__(512) void phase1_kernel(
    const float* __restrict__ x, const float* __restrict__ Wi, const float* __restrict__ bi,
    float* __restrict__ h,
    const float* __restrict__ Wdst, const float* __restrict__ Wsrc,
    const float* __restrict__ Wlin, const float* __restrict__ Wa1,
    float* __restrict__ Wall)
{
  __shared__ __align__(16) char buf[33792];
  const int bid = blockIdx.x;
  const int tid = threadIdx.x;

  // ---------------- h = relu(x@Wi + bi), 64x64 tile, 512 threads ----------------
  float* As = (float*)buf;                    // [64][68]
  float* Ws = (float*)(buf + 64 * 68 * 4);    // [64][64]
  long row0 = (long)bid * 64;
  {
    int r = tid >> 3, k8 = (tid & 7) * 8;
    float4 a0 = *(const float4*)(x + (row0 + r) * 64 + k8);
    float4 a1 = *(const float4*)(x + (row0 + r) * 64 + k8 + 4);
    *(float4*)&As[r * 68 + k8] = a0;
    *(float4*)&As[r * 68 + k8 + 4] = a1;
    float4 w0 = *(const float4*)(Wi + r * 64 + k8);
    float4 w1 = *(const float4*)(Wi + r * 64 + k8 + 4);
    *(float4*)&Ws[r * 64 + k8] = w0;
    *(float4*)&Ws[r * 64 + k8 + 4] = w1;
  }
  __syncthreads();
  {
    int tx = tid & 15, ty = tid >> 4;   // ty 0..31
    float acc[2][4] = {};
#pragma unroll 8
    for (int k = 0; k < 64; ++k) {
      float4 w = *(const float4*)&Ws[k * 64 + tx * 4];
      float a0 = As[(ty * 2 + 0) * 68 + k];
      float a1 = As[(ty * 2 + 1) * 68 + k];
      acc[0][0] += a0 * w.x; acc[0][1] += a0 * w.y; acc[0][2] += a0 * w.z; acc[0][3] += a0 * w.w;
      acc[1][0] += a1 * w.x; acc[1][1] += a1 * w.y; acc[1][2] += a1 * w.z; acc[1][3] += a1 * w.w;
    }
    float b0 = bi[tx * 4 + 0], b1 = bi[tx * 4 + 1], b2 = bi[tx * 4 + 2], b3 = bi[tx * 4 + 3];
#pragma unroll
    for (int i = 0; i < 2; ++i) {
      float4 o;
      o.x = fmaxf(acc[i][0] + b0, 0.f); o.y = fmaxf(acc[i][1] + b1, 0.f);
      o.z = fmaxf(acc[i][2] + b2, 0.f); o.w = fmaxf(acc[i][3] + b3, 0.f);
      *(float4*)(h + (row0 + ty * 2 + i) * 64 + tx * 4) = o;
    }
  }
  // ---------------- Wall: 64 entries per block, 8 lanes per entry ----------------
  {
    int e8 = tid >> 3;            // entry within block, 0..63
    int k0 = (tid & 7) * 16;      // k-chunk
    int gid = bid * 64 + e8;      // 0..16383
    int q = gid >> 12, r = (gid >> 6) & 63, c = gid & 63;
    float val;
    if (q < 2) {
      const float* W = q ? Wsrc : Wdst;
      float acc = 0.f;
#pragma unroll
      for (int k = 0; k < 16; ++k)
        acc += W[r * 128 + k0 + k] * Wa1[(k0 + k) * 64 + c];
      acc += __shfl_xor(acc, 1);
      acc += __shfl_xor(acc, 2);
      acc += __shfl_xor(acc, 4);
      val = acc;
    } else {
      val = Wlin[r * 128 + (q - 2) * 64 + c];
    }
    if ((tid & 7) == 0) Wall[r * 256 + q * 64 + c] = val;
  }
}

// =======================================================================
// K2: kNN (1024 blocks, 2 queries/wave, scalar SoA LDS — conflict-free)
//     + usv = h @ Wall (1024) + weight packs (80) in the kNN shadow.
// =======================================================================
#define KNN_NB 1024
#define UG_NB  1024
#define PK_NB  80
#define K2_GRID (KNN_NB + UG_NB + PK_NB)

__global__ __launch_bounds__(512) void knn_usv_kernel(
    const float* __restrict__ pos, int* __restrict__ nbr, float* __restrict__ rel,
    const float* __restrict__ h, const float* __restrict__ Wall,
    float* __restrict__ usv,
    const float* __restrict__ Wp2, const float* __restrict__ Wa1,
    const float* __restrict__ Wa2, const float* __restrict__ Wo,
    _Float16* __restrict__ p2p, _Float16* __restrict__ a1p, _Float16* __restrict__ a2p,
    _Float16* __restrict__ wop)
{
  __shared__ __align__(16) char buf[33792];
  const int bid = blockIdx.x;
  const int tid = threadIdx.x;

  if (bid < KNN_NB) {
    // ---------------- kNN: 16 points/block, 2 queries/wave, scalar SoA ----------------
    float* px  = (float*)buf;
    float* py  = (float*)(buf + 8192);
    float* pz  = (float*)(buf + 16384);
    float* sqs = (float*)(buf + 24576);
    int p0 = bid * 16;
    int base = (p0 >> 11) << 11;   // cloud base (128 blocks/cloud)
    for (int i = tid; i < NPTS; i += 512) {
      float xx = pos[(size_t)(base + i) * 3 + 0];
      float yy = pos[(size_t)(base + i) * 3 + 1];
      float zz = pos[(size_t)(base + i) * 3 + 2];
      px[i] = xx; py[i] = yy; pz[i] = zz;
      sqs[i] = xx * xx + yy * yy + zz * zz;
    }
    __syncthreads();
    int wid = tid >> 6, lane = tid & 63;
    int pl0 = (p0 & 2047) + wid * 2;
    int pl1 = pl0 + 1;
    float pix0 = px[pl0], piy0 = py[pl0], piz0 = pz[pl0];
    float pix1 = px[pl1], piy1 = py[pl1], piz1 = pz[pl1];

    // Stage 1: shared candidate loads; two independent per-lane top-8 streams.
    // Keys dp = (d2 - sqi) + 4 (monotone in d2, >0), packed with t.
    unsigned key0[8], key1[8];
#pragma unroll
    for (int i = 0; i < 8; ++i) { key0[i] = 0xFFFFFFFFu; key1[i] = 0xFFFFFFFFu; }
#pragma unroll
    for (int t = 0; t < 32; ++t) {
      int j = t * 64 + lane;
      float xx = px[j], yy = py[j], zz = pz[j], sq = sqs[j];   // 4 LDS, shared by both queries
      {
        float dot = pix0 * xx + piy0 * yy + piz0 * zz;
        float dp = __builtin_fmaf(-2.f, dot, sq) + 4.0f;
        unsigned kb = (__float_as_uint(dp) & 0xFFFFFFE0u) | (unsigned)t;
        kb = (j == pl0) ? 0xFFFFFFFFu : kb;
#pragma unroll
        for (int i = 0; i < 8; ++i) {
          unsigned lo = min(key0[i], kb), hi = max(key0[i], kb);
          key0[i] = lo; kb = hi;
        }
      }
      {
        float dot = pix1 * xx + piy1 * yy + piz1 * zz;
        float dp = __builtin_fmaf(-2.f, dot, sq) + 4.0f;
        unsigned kb = (__float_as_uint(dp) & 0xFFFFFFE0u) | (unsigned)t;
        kb = (j == pl1) ? 0xFFFFFFFFu : kb;
#pragma unroll
        for (int i = 0; i < 8; ++i) {
          unsigned lo = min(key1[i], kb), hi = max(key1[i], kb);
          key1[i] = lo; kb = hi;
        }
      }
    }

#pragma unroll 1
    for (int q = 0; q < 2; ++q) {
      int pl = q ? pl1 : pl0;
      int gp = base + pl;
      float pix = q ? pix1 : pix0, piy = q ? piy1 : piy0, piz = q ? piz1 : piz0;

      // Stage 2: exact f64 rerank of the 8 finalists (same formula as reference)
      double pxd = (double)pix, pyd = (double)piy, pzd = (double)piz;
      double sqi64 = pxd * pxd + pyd * pyd + pzd * pzd;
      unsigned long long kk[8];
#pragma unroll
      for (int i = 0; i < 8; ++i) {
        unsigned ky = q ? key1[i] : key0[i];
        if (ky == 0xFFFFFFFFu) { kk[i] = 0xFFFFFFFFFFFFFFFFull; continue; }
        int t = ky & 31;
        int j = t * 64 + lane;
        double xj = (double)px[j], yj = (double)py[j], zj = (double)pz[j];
        double sqj = xj * xj + yj * yj + zj * zj;
        double dot = pxd * xj + pyd * yj + pzd * zj;
        double d2 = sqi64 + sqj - 2.0 * dot;
        d2 = d2 > 0.0 ? d2 : 0.0;
        unsigned long long bits = (unsigned long long)__double_as_longlong(d2);
        kk[i] = (bits & ~0x7FFull) | (unsigned long long)j;
      }
      // sort kk[0..7] ascending: Batcher 8-element network (19 CEs)
#define CE(a, b) { unsigned long long lo_ = kk[a] < kk[b] ? kk[a] : kk[b]; \
                   unsigned long long hi_ = kk[a] < kk[b] ? kk[b] : kk[a]; \
                   kk[a] = lo_; kk[b] = hi_; }
      CE(0,1) CE(2,3) CE(4,5) CE(6,7)
      CE(0,2) CE(1,3) CE(4,6) CE(5,7)
      CE(1,2) CE(5,6) CE(0,4) CE(3,7)
      CE(1,5) CE(2,6)
      CE(1,4) CE(3,6)
      CE(2,4) CE(3,5)
      CE(3,4)
#undef CE

      // Stage 3: 16 extractions; heads always kk[0]; u32 truncated butterfly + exact fallback
      if (lane == 0) nbr[gp * KP1] = gp;
      if (lane < 3)  rel[(size_t)gp * KP1 * 3 + lane] = 0.f;   // self edge: rel = 0
      for (int it = 0; it < 16; ++it) {
        unsigned h32 = (unsigned)(kk[0] >> 32);
        unsigned key2 = (h32 & ~63u) | (unsigned)lane;
        unsigned m2 = key2;
#pragma unroll
        for (int off = 32; off > 0; off >>= 1) {
          unsigned o = __shfl_xor(m2, off);
          m2 = o < m2 ? o : m2;
        }
        bool same = ((key2 ^ m2) >> 6) == 0;
        unsigned long long ball = __ballot(same);
        int wl; unsigned jwin;
        if (__popcll(ball) == 1) {
          wl = (int)(m2 & 63u);
          unsigned lo32 = (unsigned)kk[0];
          unsigned wlo = __shfl(lo32, wl);
          jwin = wlo & 2047u;
        } else {
          // exact u64 butterfly among the tied truncated class
          unsigned long long mk = same ? kk[0] : 0xFFFFFFFFFFFFFFFFull;
#pragma unroll
          for (int off = 32; off > 0; off >>= 1) {
            unsigned long long o = __shfl_xor(mk, off);
            mk = o < mk ? o : mk;
          }
          jwin = (unsigned)(mk & 2047ull);
          wl = (int)(jwin & 63u);
        }
        if (lane == 0) nbr[gp * KP1 + 1 + it] = base + (int)jwin;
        if (lane < 3) {
          // rel = pos_i - pos_j computed here (positions already staged in LDS)
          const float* ps = lane == 0 ? px : (lane == 1 ? py : pz);
          float pi = lane == 0 ? pix : (lane == 1 ? piy : piz);
          rel[((size_t)gp * KP1 + 1 + it) * 3 + lane] = pi - ps[(int)jwin];
        }
        bool mine = (lane == wl);
#pragma unroll
        for (int i = 0; i < 7; ++i) kk[i] = mine ? kk[i + 1] : kk[i];
        kk[7] = mine ? 0xFFFFFFFFFFFFFFFFull : kk[7];
      }
    }
  } else if (bid < KNN_NB + UG_NB) {
    // ---------------- usv = h @ Wall, 64x64 tile, 512 threads ----------------
    float* As = (float*)buf;                    // [64][68]
    float* Ws = (float*)(buf + 64 * 68 * 4);    // [64][64]
    int b2 = bid - KNN_NB;
    long row0 = (long)(b2 >> 2) * 64;
    int c0 = (b2 & 3) * 64;
    {
      int r = tid >> 3, k8 = (tid & 7) * 8;
      float4 a0 = *(const float4*)(h + (row0 + r) * 64 + k8);
      float4 a1 = *(const float4*)(h + (row0 + r) * 64 + k8 + 4);
      *(float4*)&As[r * 68 + k8] = a0;
      *(float4*)&As[r * 68 + k8 + 4] = a1;
      float4 w0 = *(const float4*)(Wall + r * 256 + c0 + k8);
      float4 w1 = *(const float4*)(Wall + r * 256 + c0 + k8 + 4);
      *(float4*)&Ws[r * 64 + k8] = w0;
      *(float4*)&Ws[r * 64 + k8 + 4] = w1;
    }
    __syncthreads();
    int tx = tid & 15, ty = tid >> 4;   // ty 0..31
    float acc[2][4] = {};
#pragma unroll 8
    for (int k = 0; k < 64; ++k) {
      float4 w = *(const float4*)&Ws[k * 64 + tx * 4];
      float a0 = As[(ty * 2 + 0) * 68 + k];
      float a1 = As[(ty * 2 + 1) * 68 + k];
      acc[0][0] += a0 * w.x; acc[0][1] += a0 * w.y; acc[0][2] += a0 * w.z; acc[0][3] += a0 * w.w;
      acc[1][0] += a1 * w.x; acc[1][1] += a1 * w.y; acc[1][2] += a1 * w.z; acc[1][3] += a1 * w.w;
    }
#pragma unroll
    for (int i = 0; i < 2; ++i) {
      float4 o;
      o.x = acc[i][0]; o.y = acc[i][1]; o.z = acc[i][2]; o.w = acc[i][3];
      *(float4*)(usv + (row0 + ty * 2 + i) * 256 + c0 + tx * 4) = o;
    }
  } else {
    // ---------------- packw (consumed only by edge kernel) ----------------
    int gid = (bid - KNN_NB - UG_NB) * 512 + tid;   // 0..40959
    if (gid < 24576) {
      int m = gid >> 13;
      int r = gid & 8191;
      int tl = r >> 9;
      int l  = (r >> 3) & 63;
      int j  = r & 7;
      const float* src; _Float16* dst; int N, kt, nt;
      if (m == 0)      { src = Wp2; dst = p2p; N = 128; kt = tl & 1; nt = tl >> 1; }
      else if (m == 1) { src = Wa1; dst = a1p; N = 64;  kt = tl & 3; nt = tl >> 2; }
      else             { src = Wa2; dst = a2p; N = 128; kt = tl & 1; nt = tl >> 1; }
      int k = kt * 32 + (l >> 4) * 8 + j;
      int n = nt * 16 + (l & 15);
      dst[r] = (_Float16)src[k * N + n];
    } else {
      // Wo [128][128] -> B fragments, kt = tl&3, nt = tl>>2
      int r = gid - 24576;          // 0..16383
      int tl = r >> 9;              // 0..31
      int l  = (r >> 3) & 63;
      int j  = r & 7;
      int kt = tl & 3, nt = tl >> 2;
      int k = kt * 32 + (l >> 4) * 8 + j;
      int n = nt * 16 + (l & 15);
      wop[r] = (_Float16)Wo[k * 128 + n];
    }
  }
}

// ---------------- fused edge kernel: pos_nn + attn_nn (f16 MFMA) + softmax + mean + lin_out ----------------
__global__ __launch_bounds__(512, 6) void edge_kernel(
    const int* __restrict__ nbr,
    const float* __restrict__ usv,
    const float* __restrict__ rel,
    const float* __restrict__ Wp1, const float* __restrict__ bp1,
    const float* __restrict__ bp2, const float* __restrict__ ba1, const float* __restrict__ ba2,
    const _Float16* __restrict__ Wp2p, const _Float16* __restrict__ Wa1p, const _Float16* __restrict__ Wa2p,
    const _Float16* __restrict__ Wop, const float* __restrict__ bo,
    float* __restrict__ out)
{
  __shared__ __align__(16) char smem[EDGE_SMEM];
  int* nbr_s = (int*)(smem + NBR_OFF);
  const int tid = threadIdx.x;
  const int lane = tid & 63;
  const int wid = tid >> 6;
  // XCD-chunked swizzle: XCD k owns p-blocks [k*512,(k+1)*512) == exactly cloud k
  const int bid = blockIdx.x;
  const int pb = ((bid & 7) << 9) | (bid >> 3);
  const int p0 = pb * PGPT;

  // T14: issue the P5 v-gather NOW; nbr row via wave-uniform global s_loads (SMEM pipe).
  const int pp5 = tid >> 7;            // wave-uniform (wid>>1)
  const int c5 = tid & 127;
  float vreg[KP1];
  {
    const int* __restrict__ nrow = nbr + (size_t)(p0 + pp5) * KP1;
#pragma unroll
    for (int k = 0; k < KP1; ++k) {
      int jv = nrow[k];                            // s_load (wave-uniform)
      vreg[k] = usv[(size_t)jv * 256 + 128 + c5];  // coalesced v-gather
    }
  }

  // P0: stage neighbor list (used by P1's wave-uniform j reads)
  if (tid < ROWS) nbr_s[tid] = (tid < EDGES) ? nbr[p0 * KP1 + tid] : p0;
  __syncthreads();

  // P1: stage bias rows (u_i - s_j + ba1) f16 and compute pos_nn hidden ph (f16), swizzled.
  // Loads batched: all 20 v-gathers issued before any consumption (one latency
  // round-trip instead of ten). rel loads are wave-uniform s_loads, kept in-loop.
  {
    float w1x = Wp1[lane], w1y = Wp1[64 + lane], w1z = Wp1[128 + lane], b1 = bp1[lane];
    float b1a = ba1[lane];
    const float* relb = rel + (size_t)p0 * (KP1 * 3);
    int ebv[10];
    float sv[10], uu[10];
#pragma unroll
    for (int i = 0; i < 10; ++i) {
      int e = wid + i * 8;
      int eb = __builtin_amdgcn_readfirstlane(min(e, EDGES - 1));
      ebv[i] = eb;
      int p = (eb * 241) >> 12;          // eb/17 exact for eb<272
      int j = __builtin_amdgcn_readfirstlane(nbr_s[eb]);
      sv[i] = usv[(size_t)j * 256 + 64 + lane];          // coalesced
      uu[i] = usv[(size_t)(p0 + p) * 256 + lane];        // coalesced, L1-hot
    }
#pragma unroll
    for (int i = 0; i < 10; ++i) {
      int e = wid + i * 8;
      int eb = ebv[i];
      *(_Float16*)(smem + SJ_OFF + swzA(e, lane * 2)) = (_Float16)(uu[i] - sv[i] + b1a);
      float rx = relb[eb * 3 + 0];
      float ry = relb[eb * 3 + 1];
      float rz = relb[eb * 3 + 2];
      float acc = fmaxf(b1 + rx * w1x + ry * w1y + rz * w1z, 0.f);
      *(_Float16*)(smem + PH_OFF + swzA(e, lane * 2)) = (_Float16)acc;
    }
  }
  __syncthreads();

  const int rl = lane & 15;
  const int kl = lane >> 4;

  // P2: delta = relu(ph @ Wp2 + bp2)  [80 x 128], K=64
  {
    int nt = wid;  // 0..7
    h8 b0 = *(const h8*)(Wp2p + ((size_t)(nt * 2 + 0) * 64 + lane) * 8);
    h8 b1 = *(const h8*)(Wp2p + ((size_t)(nt * 2 + 1) * 64 + lane) * 8);
    int col = nt * 16 + rl;
    float bias2 = bp2[col];
    for (int mt = 0; mt < MT; ++mt) {
      int arow = mt * 16 + rl;
      h8 a0 = *(const h8*)(smem + PH_OFF + swzA(arow, kl * 16));
      h8 a1 = *(const h8*)(smem + PH_OFF + swzA(arow, 64 + kl * 16));
      fx4 acc = {0.f, 0.f, 0.f, 0.f};
      acc = __builtin_amdgcn_mfma_f32_16x16x32_f16(a0, b0, acc, 0, 0, 0);
      acc = __builtin_amdgcn_mfma_f32_16x16x32_f16(a1, b1, acc, 0, 0, 0);
#pragma unroll
      for (int jj = 0; jj < 4; ++jj) {
        int orow = mt * 16 + kl * 4 + jj;
        float val = fmaxf(acc[jj] + bias2, 0.f);
        *(_Float16*)(smem + DELTA_OFF + swzB(orow, col * 2)) = (_Float16)val;
      }
    }
  }
  __syncthreads();

  // P3: t = delta @ Wa1 (K=128); ah = relu(t + bias_row) -> stored in ph space [80x64]
  // bias_row = u_i - s_j + ba1, folded in P1.
  {
    int nt = wid & 3;
    h8 b[4];
#pragma unroll
    for (int kt = 0; kt < 4; ++kt)
      b[kt] = *(const h8*)(Wa1p + ((size_t)(nt * 4 + kt) * 64 + lane) * 8);
    int hcol = nt * 16 + rl;
    for (int mt = (wid >> 2); mt < MT; mt += 2) {
      int arow = mt * 16 + rl;
      fx4 acc = {0.f, 0.f, 0.f, 0.f};
#pragma unroll
      for (int kt = 0; kt < 4; ++kt) {
        h8 a = *(const h8*)(smem + DELTA_OFF + swzB(arow, kt * 64 + kl * 16));
        acc = __builtin_amdgcn_mfma_f32_16x16x32_f16(a, b[kt], acc, 0, 0, 0);
      }
#pragma unroll
      for (int jj = 0; jj < 4; ++jj) {
        int orow = mt * 16 + kl * 4 + jj;
        float bb = (float)*(const _Float16*)(smem + SJ_OFF + swzA(orow, hcol * 2));
        float val = fmaxf(acc[jj] + bb, 0.f);
        *(_Float16*)(smem + PH_OFF + swzA(orow, hcol * 2)) = (_Float16)val;
      }
    }
  }
  __syncthreads();   // <- after this barrier SJ is dead; ATT (same bytes) becomes live

  // P4: attn = relu(ah @ Wa2 + ba2) -> TRANSPOSED att_T[ch][pp*20 + k], guarded to real edges
  {
    int nt = wid;
    h8 b0 = *(const h8*)(Wa2p + ((size_t)(nt * 2 + 0) * 64 + lane) * 8);
    h8 b1 = *(const h8*)(Wa2p + ((size_t)(nt * 2 + 1) * 64 + lane) * 8);
    int col = nt * 16 + rl;
    float b2v = ba2[col];
    char* cbase = smem + ATT_OFF + col * ATT_RB;
    for (int mt = 0; mt < MT; ++mt) {
      int arow = mt * 16 + rl;
      h8 a0 = *(const h8*)(smem + PH_OFF + swzA(arow, kl * 16));
      h8 a1 = *(const h8*)(smem + PH_OFF + swzA(arow, 64 + kl * 16));
      fx4 acc = {0.f, 0.f, 0.f, 0.f};
      acc = __builtin_amdgcn_mfma_f32_16x16x32_f16(a0, b0, acc, 0, 0, 0);
      acc = __builtin_amdgcn_mfma_f32_16x16x32_f16(a1, b1, acc, 0, 0, 0);
#pragma unroll
      for (int jj = 0; jj < 4; ++jj) {
        int orow = mt * 16 + kl * 4 + jj;
        if (orow < EDGES) {
          int pp = (orow * 241) >> 12;
          float val = fmaxf(acc[jj] + b2v, 0.f);
          *(_Float16*)(cbase + (orow + 3 * pp) * 2) = (_Float16)val;  // row_store = pp*20 + k
        }
      }
    }
  }
  __syncthreads();

  // P6 prefetch: Wo B-fragments (consumed after P5; latency hidden by softmax)
  h8 bw[4];
#pragma unroll
  for (int kt = 0; kt < 4; ++kt)
    bw[kt] = *(const h8*)(Wop + ((size_t)(wid * 4 + kt) * 64 + lane) * 8);

  // P5: per-channel softmax over 17 neighbors + weighted mean of (v_j + delta) -> opre f16 in PH
  {
    int r0 = pp5 * KP1;
    const char* abase = smem + ATT_OFF + c5 * ATT_RB + pp5 * 40;
    h4 t0 = *(const h4*)(abase + 0);
    h4 t1 = *(const h4*)(abase + 8);
    h4 t2 = *(const h4*)(abase + 16);
    h4 t3 = *(const h4*)(abase + 24);
    float att[KP1];
#pragma unroll
    for (int q = 0; q < 4; ++q) {
      att[0 + q]  = (float)t0[q];
      att[4 + q]  = (float)t1[q];
      att[8 + q]  = (float)t2[q];
      att[12 + q] = (float)t3[q];
    }
    att[16] = (float)*(const _Float16*)(abase + 32);
    // max tree (short dependency chain; max is exact so any association is identical)
    float m8[8];
#pragma unroll
    for (int k = 0; k < 8; ++k) m8[k] = fmaxf(att[k], att[k + 8]);
    float m4a = fmaxf(m8[0], m8[1]), m4b = fmaxf(m8[2], m8[3]);
    float m4c = fmaxf(m8[4], m8[5]), m4d = fmaxf(m8[6], m8[7]);
    float m = fmaxf(fmaxf(fmaxf(m4a, m4b), fmaxf(m4c, m4d)), att[16]);
    float den = 0.f;
#pragma unroll
    for (int k = 0; k < KP1; ++k) { att[k] = __expf(att[k] - m); den += att[k]; }
    float inv = 1.f / (den * 17.f);
    float acc = 0.f;
#pragma unroll
    for (int k = 0; k < KP1; ++k) {
      float dd = (float)*(const _Float16*)(smem + DELTA_OFF + swzB(r0 + k, c5 * 2));
      acc += att[k] * (vreg[k] + dd);
    }
    // opre row pp5 (0..3), col c5 -> f16 (RTN) into dead PH region, swzB layout
    *(_Float16*)(smem + PH_OFF + swzB(pp5, c5 * 2)) = (_Float16)(acc * inv);
  }
  __syncthreads();

  // P6: out = relu(opre @ Wo + bo). One 16-row M-tile; rows 0..3 real, 4..15 stale-but-finite.
  {
    fx4 acc = {0.f, 0.f, 0.f, 0.f};
#pragma unroll
    for (int kt = 0; kt < 4; ++kt) {
      h8 a = *(const h8*)(smem + PH_OFF + swzB(rl, kt * 64 + kl * 16));
      acc = __builtin_amdgcn_mfma_f32_16x16x32_f16(a, bw[kt], acc, 0, 0, 0);
    }
    if (kl == 0) {               // acc rows 0..3 = the block's 4 points
      int col = wid * 16 + rl;
      float bov = bo[col];
#pragma unroll
      for (int jj = 0; jj < 4; ++jj)
        out[(size_t)(p0 + jj) * 128 + col] = fmaxf(acc[jj] + bov, 0.f);
    }
  }
}

extern "C" void kernel_launch(void* const* d_in, const int* in_sizes, int n_in,
                              void* d_out, int out_size, void* d_ws, size_t ws_size,
                              hipStream_t stream) {
  const float* x    = (const float*)d_in[0];
  const float* pos  = (const float*)d_in[1];
  const float* Wi   = (const float*)d_in[3];
  const float* bi   = (const float*)d_in[4];
  const float* Wsrc = (const float*)d_in[5];
  const float* Wdst = (const float*)d_in[6];
  const float* Wlin = (const float*)d_in[7];
  const float* Wp1  = (const float*)d_in[8];
  const float* bp1  = (const float*)d_in[9];
  const float* Wp2  = (const float*)d_in[10];
  const float* bp2  = (const float*)d_in[11];
  const float* Wa1  = (const float*)d_in[12];
  const float* ba1  = (const float*)d_in[13];
  const float* Wa2  = (const float*)d_in[14];
  const float* ba2  = (const float*)d_in[15];
  const float* Wo   = (const float*)d_in[16];
  const float* bo   = (const float*)d_in[17];
  float* out = (float*)d_out;

  char* ws = (char*)d_ws;
  float* h    = (float*)(ws + 0);          // 16384x64   (4 MB)
  float* usv  = (float*)(ws + 4194304);    // 16384x256  (16 MB): [u|s|v]
  float* Wall = (float*)(ws + 20971520);   // 64x256 (64 KB)
  float* rel  = (float*)(ws + 21037056);   // 16384x17x3 f32 (3.34 MB)
  int*   nbr  = (int*)  (ws + 29360128);   // 16384x17
  _Float16* p2p = (_Float16*)(ws + 30474240);  // 16 KB
  _Float16* a1p = (_Float16*)(ws + 30490624);
  _Float16* a2p = (_Float16*)(ws + 30507008);
  _Float16* wop = (_Float16*)(ws + 30523392);  // 32 KB (Wo packed)

  phase1_kernel<<<P1_GRID, 512, 0, stream>>>(x, Wi, bi, h, Wdst, Wsrc, Wlin, Wa1, Wall);
  knn_usv_kernel<<<K2_GRID, 512, 0, stream>>>(pos, nbr, rel, h, Wall, usv,
                                              Wp2, Wa1, Wa2, Wo, p2p, a1p, a2p, wop);
  edge_kernel<<<4096, 512, 0, stream>>>(nbr, usv, rel, Wp1, bp1, bp2, ba1, ba2,
                                        p2p, a1p, a2p, wop, bo, out);
}

// Round 11
// 125.194 us; speedup vs baseline: 1.1903x; 1.0191x over previous
//
#include <hip/hip_runtime.h>
#include <hip/hip_fp16.h>

typedef _Float16 h8 __attribute__((ext_vector_type(8)));
typedef _Float16 h4 __attribute__((ext_vector_type(4)));
typedef float fx4 __attribute__((ext_vector_type(4)));

#define NPTS   2048
#define KP1    17
#define PGPT   4          // points per edge-block
#define EDGES  68         // PGPT*17 real edges
#define ROWS   80         // padded to 5 M-tiles
#define MT     5
// static LDS layout for edge kernel (bytes) -- total 52224, x3 -> 3 blocks/CU
// SJ (bias rows u-s+ba1) overlays ATT: SJ live P1->P3, ATT live P4->P5 (post-P3 barrier).
// PH holds ph (P1-P2), ah (P3-P4), then opre f16 [16][128] swzB (P5-P6).
// nbr staging eliminated: all nbr reads are wave-uniform global s_loads (SMEM pipe).
#define DELTA_OFF 0        // f16 [80][128], rowbytes 256, swizzled          (20480)
#define PH_OFF    20480    // f16 [80][64],  rowbytes 128, swizzled (ph->ah) (10240)
#define ATT_OFF   30720    // f16 att_T[128 ch][84 rows], rowbytes 168       (21504)
#define SJ_OFF    30720    // f16 [80][64],  rowbytes 128, swizzled — OVERLAYS ATT
#define EDGE_SMEM 52224
#define ATT_RB    168

__device__ __forceinline__ int swzA(int row, int bytecol) {  // rowbytes 128
  return (row << 7) + (bytecol ^ ((row & 7) << 4));
}
__device__ __forceinline__ int swzB(int row, int bytecol) {  // rowbytes 256
  return (row << 8) + (bytecol ^ ((row & 7) << 4));
}

// =======================================================================
// K1: minimal serial prefix — h = relu(x@Wi+bi) with Wall folded into the
// same 256 blocks (64 Wall entries each, 8 lanes/entry), so K1 is exactly
// 1 block/CU and its duration is a single block's time.
// =======================================================================
#define GH_NB    256
#define P1_GRID  GH_NB

__global__ __launch_bounds__(512) void phase1_kernel(
    const float* __restrict__ x, const float* __restrict__ Wi, const float* __restrict__ bi,
    float* __restrict__ h,
    const float* __restrict__ Wdst, const float* __restrict__ Wsrc,
    const float* __restrict__ Wlin, const float* __restrict__ Wa1,
    float* __restrict__ Wall)
{
  __shared__ __align__(16) char buf[33792];
  const int bid = blockIdx.x;
  const int tid = threadIdx.x;

  // ---------------- h = relu(x@Wi + bi), 64x64 tile, 512 threads ----------------
  float* As = (float*)buf;                    // [64][68]
  float* Ws = (float*)(buf + 64 * 68 * 4);    // [64][64]
  long row0 = (long)bid * 64;
  {
    int r = tid >> 3, k8 = (tid & 7) * 8;
    float4 a0 = *(const float4*)(x + (row0 + r) * 64 + k8);
    float4 a1 = *(const float4*)(x + (row0 + r) * 64 + k8 + 4);
    *(float4*)&As[r * 68 + k8] = a0;
    *(float4*)&As[r * 68 + k8 + 4] = a1;
    float4 w0 = *(const float4*)(Wi + r * 64 + k8);
    float4 w1 = *(const float4*)(Wi + r * 64 + k8 + 4);
    *(float4*)&Ws[r * 64 + k8] = w0;
    *(float4*)&Ws[r * 64 + k8 + 4] = w1;
  }
  __syncthreads();
  {
    int tx = tid & 15, ty = tid >> 4;   // ty 0..31
    float acc[2][4] = {};
#pragma unroll 8
    for (int k = 0; k < 64; ++k) {
      float4 w = *(const float4*)&Ws[k * 64 + tx * 4];
      float a0 = As[(ty * 2 + 0) * 68 + k];
      float a1 = As[(ty * 2 + 1) * 68 + k];
      acc[0][0] += a0 * w.x; acc[0][1] += a0 * w.y; acc[0][2] += a0 * w.z; acc[0][3] += a0 * w.w;
      acc[1][0] += a1 * w.x; acc[1][1] += a1 * w.y; acc[1][2] += a1 * w.z; acc[1][3] += a1 * w.w;
    }
    float b0 = bi[tx * 4 + 0], b1 = bi[tx * 4 + 1], b2 = bi[tx * 4 + 2], b3 = bi[tx * 4 + 3];
#pragma unroll
    for (int i = 0; i < 2; ++i) {
      float4 o;
      o.x = fmaxf(acc[i][0] + b0, 0.f); o.y = fmaxf(acc[i][1] + b1, 0.f);
      o.z = fmaxf(acc[i][2] + b2, 0.f); o.w = fmaxf(acc[i][3] + b3, 0.f);
      *(float4*)(h + (row0 + ty * 2 + i) * 64 + tx * 4) = o;
    }
  }
  // ---------------- Wall: 64 entries per block, 8 lanes per entry ----------------
  {
    int e8 = tid >> 3;            // entry within block, 0..63
    int k0 = (tid & 7) * 16;      // k-chunk
    int gid = bid * 64 + e8;      // 0..16383
    int q = gid >> 12, r = (gid >> 6) & 63, c = gid & 63;
    float val;
    if (q < 2) {
      const float* W = q ? Wsrc : Wdst;
      float acc = 0.f;
#pragma unroll
      for (int k = 0; k < 16; ++k)
        acc += W[r * 128 + k0 + k] * Wa1[(k0 + k) * 64 + c];
      acc += __shfl_xor(acc, 1);
      acc += __shfl_xor(acc, 2);
      acc += __shfl_xor(acc, 4);
      val = acc;
    } else {
      val = Wlin[r * 128 + (q - 2) * 64 + c];
    }
    if ((tid & 7) == 0) Wall[r * 256 + q * 64 + c] = val;
  }
}

// =======================================================================
// K2: kNN (1024 blocks, 2 queries/wave, scalar SoA LDS — conflict-free)
//     + usv = h @ Wall (1024) + weight packs (80) in the kNN shadow.
// =======================================================================
#define KNN_NB 1024
#define UG_NB  1024
#define PK_NB  80
#define K2_GRID (KNN_NB + UG_NB + PK_NB)

__global__ __launch_bounds__(512) void knn_usv_kernel(
    const float* __restrict__ pos, int* __restrict__ nbr, float* __restrict__ rel,
    const float* __restrict__ h, const float* __restrict__ Wall,
    float* __restrict__ usv,
    const float* __restrict__ Wp2, const float* __restrict__ Wa1,
    const float* __restrict__ Wa2, const float* __restrict__ Wo,
    _Float16* __restrict__ p2p, _Float16* __restrict__ a1p, _Float16* __restrict__ a2p,
    _Float16* __restrict__ wop)
{
  __shared__ __align__(16) char buf[33792];
  const int bid = blockIdx.x;
  const int tid = threadIdx.x;

  if (bid < KNN_NB) {
    // ---------------- kNN: 16 points/block, 2 queries/wave, scalar SoA ----------------
    float* px  = (float*)buf;
    float* py  = (float*)(buf + 8192);
    float* pz  = (float*)(buf + 16384);
    float* sqs = (float*)(buf + 24576);
    int p0 = bid * 16;
    int base = (p0 >> 11) << 11;   // cloud base (128 blocks/cloud)
    for (int i = tid; i < NPTS; i += 512) {
      float xx = pos[(size_t)(base + i) * 3 + 0];
      float yy = pos[(size_t)(base + i) * 3 + 1];
      float zz = pos[(size_t)(base + i) * 3 + 2];
      px[i] = xx; py[i] = yy; pz[i] = zz;
      sqs[i] = xx * xx + yy * yy + zz * zz;
    }
    __syncthreads();
    int wid = tid >> 6, lane = tid & 63;
    int pl0 = (p0 & 2047) + wid * 2;
    int pl1 = pl0 + 1;
    float pix0 = px[pl0], piy0 = py[pl0], piz0 = pz[pl0];
    float pix1 = px[pl1], piy1 = py[pl1], piz1 = pz[pl1];

    // Stage 1: shared candidate loads; two independent per-lane top-8 streams.
    // Keys dp = (d2 - sqi) + 4 (monotone in d2, >0), packed with t.
    unsigned key0[8], key1[8];
#pragma unroll
    for (int i = 0; i < 8; ++i) { key0[i] = 0xFFFFFFFFu; key1[i] = 0xFFFFFFFFu; }
#pragma unroll
    for (int t = 0; t < 32; ++t) {
      int j = t * 64 + lane;
      float xx = px[j], yy = py[j], zz = pz[j], sq = sqs[j];   // 4 LDS, shared by both queries
      {
        float dot = pix0 * xx + piy0 * yy + piz0 * zz;
        float dp = __builtin_fmaf(-2.f, dot, sq) + 4.0f;
        unsigned kb = (__float_as_uint(dp) & 0xFFFFFFE0u) | (unsigned)t;
        kb = (j == pl0) ? 0xFFFFFFFFu : kb;
#pragma unroll
        for (int i = 0; i < 8; ++i) {
          unsigned lo = min(key0[i], kb), hi = max(key0[i], kb);
          key0[i] = lo; kb = hi;
        }
      }
      {
        float dot = pix1 * xx + piy1 * yy + piz1 * zz;
        float dp = __builtin_fmaf(-2.f, dot, sq) + 4.0f;
        unsigned kb = (__float_as_uint(dp) & 0xFFFFFFE0u) | (unsigned)t;
        kb = (j == pl1) ? 0xFFFFFFFFu : kb;
#pragma unroll
        for (int i = 0; i < 8; ++i) {
          unsigned lo = min(key1[i], kb), hi = max(key1[i], kb);
          key1[i] = lo; kb = hi;
        }
      }
    }

#pragma unroll 1
    for (int q = 0; q < 2; ++q) {
      int pl = q ? pl1 : pl0;
      int gp = base + pl;
      float pix = q ? pix1 : pix0, piy = q ? piy1 : piy0, piz = q ? piz1 : piz0;

      // Stage 2: exact f64 rerank of the 8 finalists (same formula as reference)
      double pxd = (double)pix, pyd = (double)piy, pzd = (double)piz;
      double sqi64 = pxd * pxd + pyd * pyd + pzd * pzd;
      unsigned long long kk[8];
#pragma unroll
      for (int i = 0; i < 8; ++i) {
        unsigned ky = q ? key1[i] : key0[i];
        if (ky == 0xFFFFFFFFu) { kk[i] = 0xFFFFFFFFFFFFFFFFull; continue; }
        int t = ky & 31;
        int j = t * 64 + lane;
        double xj = (double)px[j], yj = (double)py[j], zj = (double)pz[j];
        double sqj = xj * xj + yj * yj + zj * zj;
        double dot = pxd * xj + pyd * yj + pzd * zj;
        double d2 = sqi64 + sqj - 2.0 * dot;
        d2 = d2 > 0.0 ? d2 : 0.0;
        unsigned long long bits = (unsigned long long)__double_as_longlong(d2);
        kk[i] = (bits & ~0x7FFull) | (unsigned long long)j;
      }
      // sort kk[0..7] ascending: Batcher 8-element network (19 CEs)
#define CE(a, b) { unsigned long long lo_ = kk[a] < kk[b] ? kk[a] : kk[b]; \
                   unsigned long long hi_ = kk[a] < kk[b] ? kk[b] : kk[a]; \
                   kk[a] = lo_; kk[b] = hi_; }
      CE(0,1) CE(2,3) CE(4,5) CE(6,7)
      CE(0,2) CE(1,3) CE(4,6) CE(5,7)
      CE(1,2) CE(5,6) CE(0,4) CE(3,7)
      CE(1,5) CE(2,6)
      CE(1,4) CE(3,6)
      CE(2,4) CE(3,5)
      CE(3,4)
#undef CE

      // Stage 3: 16 extractions; heads always kk[0]; u32 truncated butterfly + exact fallback
      if (lane == 0) nbr[gp * KP1] = gp;
      if (lane < 3)  rel[(size_t)gp * KP1 * 3 + lane] = 0.f;   // self edge: rel = 0
      for (int it = 0; it < 16; ++it) {
        unsigned h32 = (unsigned)(kk[0] >> 32);
        unsigned key2 = (h32 & ~63u) | (unsigned)lane;
        unsigned m2 = key2;
#pragma unroll
        for (int off = 32; off > 0; off >>= 1) {
          unsigned o = __shfl_xor(m2, off);
          m2 = o < m2 ? o : m2;
        }
        bool same = ((key2 ^ m2) >> 6) == 0;
        unsigned long long ball = __ballot(same);
        int wl; unsigned jwin;
        if (__popcll(ball) == 1) {
          wl = (int)(m2 & 63u);
          unsigned lo32 = (unsigned)kk[0];
          unsigned wlo = __shfl(lo32, wl);
          jwin = wlo & 2047u;
        } else {
          // exact u64 butterfly among the tied truncated class
          unsigned long long mk = same ? kk[0] : 0xFFFFFFFFFFFFFFFFull;
#pragma unroll
          for (int off = 32; off > 0; off >>= 1) {
            unsigned long long o = __shfl_xor(mk, off);
            mk = o < mk ? o : mk;
          }
          jwin = (unsigned)(mk & 2047ull);
          wl = (int)(jwin & 63u);
        }
        if (lane == 0) nbr[gp * KP1 + 1 + it] = base + (int)jwin;
        if (lane < 3) {
          // rel = pos_i - pos_j computed here (positions already staged in LDS)
          const float* ps = lane == 0 ? px : (lane == 1 ? py : pz);
          float pi = lane == 0 ? pix : (lane == 1 ? piy : piz);
          rel[((size_t)gp * KP1 + 1 + it) * 3 + lane] = pi - ps[(int)jwin];
        }
        bool mine = (lane == wl);
#pragma unroll
        for (int i = 0; i < 7; ++i) kk[i] = mine ? kk[i + 1] : kk[i];
        kk[7] = mine ? 0xFFFFFFFFFFFFFFFFull : kk[7];
      }
    }
  } else if (bid < KNN_NB + UG_NB) {
    // ---------------- usv = h @ Wall, 64x64 tile, 512 threads ----------------
    float* As = (float*)buf;                    // [64][68]
    float* Ws = (float*)(buf + 64 * 68 * 4);    // [64][64]
    int b2 = bid - KNN_NB;
    long row0 = (long)(b2 >> 2) * 64;
    int c0 = (b2 & 3) * 64;
    {
      int r = tid >> 3, k8 = (tid & 7) * 8;
      float4 a0 = *(const float4*)(h + (row0 + r) * 64 + k8);
      float4 a1 = *(const float4*)(h + (row0 + r) * 64 + k8 + 4);
      *(float4*)&As[r * 68 + k8] = a0;
      *(float4*)&As[r * 68 + k8 + 4] = a1;
      float4 w0 = *(const float4*)(Wall + r * 256 + c0 + k8);
      float4 w1 = *(const float4*)(Wall + r * 256 + c0 + k8 + 4);
      *(float4*)&Ws[r * 64 + k8] = w0;
      *(float4*)&Ws[r * 64 + k8 + 4] = w1;
    }
    __syncthreads();
    int tx = tid & 15, ty = tid >> 4;   // ty 0..31
    float acc[2][4] = {};
#pragma unroll 8
    for (int k = 0; k < 64; ++k) {
      float4 w = *(const float4*)&Ws[k * 64 + tx * 4];
      float a0 = As[(ty * 2 + 0) * 68 + k];
      float a1 = As[(ty * 2 + 1) * 68 + k];
      acc[0][0] += a0 * w.x; acc[0][1] += a0 * w.y; acc[0][2] += a0 * w.z; acc[0][3] += a0 * w.w;
      acc[1][0] += a1 * w.x; acc[1][1] += a1 * w.y; acc[1][2] += a1 * w.z; acc[1][3] += a1 * w.w;
    }
#pragma unroll
    for (int i = 0; i < 2; ++i) {
      float4 o;
      o.x = acc[i][0]; o.y = acc[i][1]; o.z = acc[i][2]; o.w = acc[i][3];
      *(float4*)(usv + (row0 + ty * 2 + i) * 256 + c0 + tx * 4) = o;
    }
  } else {
    // ---------------- packw (consumed only by edge kernel) ----------------
    int gid = (bid - KNN_NB - UG_NB) * 512 + tid;   // 0..40959
    if (gid < 24576) {
      int m = gid >> 13;
      int r = gid & 8191;
      int tl = r >> 9;
      int l  = (r >> 3) & 63;
      int j  = r & 7;
      const float* src; _Float16* dst; int N, kt, nt;
      if (m == 0)      { src = Wp2; dst = p2p; N = 128; kt = tl & 1; nt = tl >> 1; }
      else if (m == 1) { src = Wa1; dst = a1p; N = 64;  kt = tl & 3; nt = tl >> 2; }
      else             { src = Wa2; dst = a2p; N = 128; kt = tl & 1; nt = tl >> 1; }
      int k = kt * 32 + (l >> 4) * 8 + j;
      int n = nt * 16 + (l & 15);
      dst[r] = (_Float16)src[k * N + n];
    } else {
      // Wo [128][128] -> B fragments, kt = tl&3, nt = tl>>2
      int r = gid - 24576;          // 0..16383
      int tl = r >> 9;              // 0..31
      int l  = (r >> 3) & 63;
      int j  = r & 7;
      int kt = tl & 3, nt = tl >> 2;
      int k = kt * 32 + (l >> 4) * 8 + j;
      int n = nt * 16 + (l & 15);
      wop[r] = (_Float16)Wo[k * 128 + n];
    }
  }
}

// ---------------- fused edge kernel: pos_nn + attn_nn (f16 MFMA) + softmax + mean + lin_out ----------------
__global__ __launch_bounds__(512, 6) void edge_kernel(
    const int* __restrict__ nbr,
    const float* __restrict__ usv,
    const float* __restrict__ rel,
    const float* __restrict__ Wp1, const float* __restrict__ bp1,
    const float* __restrict__ bp2, const float* __restrict__ ba1, const float* __restrict__ ba2,
    const _Float16* __restrict__ Wp2p, const _Float16* __restrict__ Wa1p, const _Float16* __restrict__ Wa2p,
    const _Float16* __restrict__ Wop, const float* __restrict__ bo,
    float* __restrict__ out)
{
  __shared__ __align__(16) char smem[EDGE_SMEM];
  const int tid = threadIdx.x;
  const int lane = tid & 63;
  const int wid = tid >> 6;
  // XCD-chunked swizzle: XCD k owns p-blocks [k*512,(k+1)*512) == exactly cloud k
  const int bid = blockIdx.x;
  const int pb = ((bid & 7) << 9) | (bid >> 3);
  const int p0 = pb * PGPT;

  // T14: issue the P5 v-gather NOW; nbr row via wave-uniform global s_loads (SMEM pipe).
  const int pp5 = tid >> 7;            // wave-uniform (wid>>1)
  const int c5 = tid & 127;
  float vreg[KP1];
  {
    const int* __restrict__ nrow = nbr + (size_t)(p0 + pp5) * KP1;
#pragma unroll
    for (int k = 0; k < KP1; ++k) {
      int jv = nrow[k];                            // s_load (wave-uniform)
      vreg[k] = usv[(size_t)jv * 256 + 128 + c5];  // coalesced v-gather
    }
  }

  // P1 (no prior barrier — nbr staging eliminated): stage bias rows
  // (u_i - s_j + ba1) f16 and compute pos_nn hidden ph (f16), swizzled.
  // All j come from wave-uniform global s_loads (L2-hot 272 B region);
  // loads batched: all 20 v-gathers in flight before any consumption.
  {
    float w1x = Wp1[lane], w1y = Wp1[64 + lane], w1z = Wp1[128 + lane], b1 = bp1[lane];
    float b1a = ba1[lane];
    const float* relb = rel + (size_t)p0 * (KP1 * 3);
    const int* __restrict__ nb = nbr + (size_t)p0 * KP1;
    int ebv[10];
    float sv[10], uu[10];
#pragma unroll
    for (int i = 0; i < 10; ++i) {
      int e = wid + i * 8;
      int eb = __builtin_amdgcn_readfirstlane(min(e, EDGES - 1));
      ebv[i] = eb;
      int p = (eb * 241) >> 12;          // eb/17 exact for eb<272
      int j = __builtin_amdgcn_readfirstlane(nb[eb]);     // s_load (wave-uniform)
      sv[i] = usv[(size_t)j * 256 + 64 + lane];          // coalesced
      uu[i] = usv[(size_t)(p0 + p) * 256 + lane];        // coalesced, L1-hot
    }
#pragma unroll
    for (int i = 0; i < 10; ++i) {
      int e = wid + i * 8;
      int eb = ebv[i];
      *(_Float16*)(smem + SJ_OFF + swzA(e, lane * 2)) = (_Float16)(uu[i] - sv[i] + b1a);
      float rx = relb[eb * 3 + 0];
      float ry = relb[eb * 3 + 1];
      float rz = relb[eb * 3 + 2];
      float acc = fmaxf(b1 + rx * w1x + ry * w1y + rz * w1z, 0.f);
      *(_Float16*)(smem + PH_OFF + swzA(e, lane * 2)) = (_Float16)acc;
    }
  }
  __syncthreads();

  const int rl = lane & 15;
  const int kl = lane >> 4;

  // P2: delta = relu(ph @ Wp2 + bp2)  [80 x 128], K=64
  {
    int nt = wid;  // 0..7
    h8 b0 = *(const h8*)(Wp2p + ((size_t)(nt * 2 + 0) * 64 + lane) * 8);
    h8 b1 = *(const h8*)(Wp2p + ((size_t)(nt * 2 + 1) * 64 + lane) * 8);
    int col = nt * 16 + rl;
    float bias2 = bp2[col];
    for (int mt = 0; mt < MT; ++mt) {
      int arow = mt * 16 + rl;
      h8 a0 = *(const h8*)(smem + PH_OFF + swzA(arow, kl * 16));
      h8 a1 = *(const h8*)(smem + PH_OFF + swzA(arow, 64 + kl * 16));
      fx4 acc = {0.f, 0.f, 0.f, 0.f};
      acc = __builtin_amdgcn_mfma_f32_16x16x32_f16(a0, b0, acc, 0, 0, 0);
      acc = __builtin_amdgcn_mfma_f32_16x16x32_f16(a1, b1, acc, 0, 0, 0);
#pragma unroll
      for (int jj = 0; jj < 4; ++jj) {
        int orow = mt * 16 + kl * 4 + jj;
        float val = fmaxf(acc[jj] + bias2, 0.f);
        *(_Float16*)(smem + DELTA_OFF + swzB(orow, col * 2)) = (_Float16)val;
      }
    }
  }
  __syncthreads();

  // P3: t = delta @ Wa1 (K=128); ah = relu(t + bias_row) -> stored in ph space [80x64]
  // bias_row = u_i - s_j + ba1, folded in P1.
  {
    int nt = wid & 3;
    h8 b[4];
#pragma unroll
    for (int kt = 0; kt < 4; ++kt)
      b[kt] = *(const h8*)(Wa1p + ((size_t)(nt * 4 + kt) * 64 + lane) * 8);
    int hcol = nt * 16 + rl;
    for (int mt = (wid >> 2); mt < MT; mt += 2) {
      int arow = mt * 16 + rl;
      fx4 acc = {0.f, 0.f, 0.f, 0.f};
#pragma unroll
      for (int kt = 0; kt < 4; ++kt) {
        h8 a = *(const h8*)(smem + DELTA_OFF + swzB(arow, kt * 64 + kl * 16));
        acc = __builtin_amdgcn_mfma_f32_16x16x32_f16(a, b[kt], acc, 0, 0, 0);
      }
#pragma unroll
      for (int jj = 0; jj < 4; ++jj) {
        int orow = mt * 16 + kl * 4 + jj;
        float bb = (float)*(const _Float16*)(smem + SJ_OFF + swzA(orow, hcol * 2));
        float val = fmaxf(acc[jj] + bb, 0.f);
        *(_Float16*)(smem + PH_OFF + swzA(orow, hcol * 2)) = (_Float16)val;
      }
    }
  }
  __syncthreads();   // <- after this barrier SJ is dead; ATT (same bytes) becomes live

  // P4: attn = relu(ah @ Wa2 + ba2) -> TRANSPOSED att_T[ch][pp*20 + k], guarded to real edges
  {
    int nt = wid;
    h8 b0 = *(const h8*)(Wa2p + ((size_t)(nt * 2 + 0) * 64 + lane) * 8);
    h8 b1 = *(const h8*)(Wa2p + ((size_t)(nt * 2 + 1) * 64 + lane) * 8);
    int col = nt * 16 + rl;
    float b2v = ba2[col];
    char* cbase = smem + ATT_OFF + col * ATT_RB;
    for (int mt = 0; mt < MT; ++mt) {
      int arow = mt * 16 + rl;
      h8 a0 = *(const h8*)(smem + PH_OFF + swzA(arow, kl * 16));
      h8 a1 = *(const h8*)(smem + PH_OFF + swzA(arow, 64 + kl * 16));
      fx4 acc = {0.f, 0.f, 0.f, 0.f};
      acc = __builtin_amdgcn_mfma_f32_16x16x32_f16(a0, b0, acc, 0, 0, 0);
      acc = __builtin_amdgcn_mfma_f32_16x16x32_f16(a1, b1, acc, 0, 0, 0);
#pragma unroll
      for (int jj = 0; jj < 4; ++jj) {
        int orow = mt * 16 + kl * 4 + jj;
        if (orow < EDGES) {
          int pp = (orow * 241) >> 12;
          float val = fmaxf(acc[jj] + b2v, 0.f);
          *(_Float16*)(cbase + (orow + 3 * pp) * 2) = (_Float16)val;  // row_store = pp*20 + k
        }
      }
    }
  }
  __syncthreads();

  // P6 prefetch: Wo B-fragments (consumed after P5; latency hidden by softmax)
  h8 bw[4];
#pragma unroll
  for (int kt = 0; kt < 4; ++kt)
    bw[kt] = *(const h8*)(Wop + ((size_t)(wid * 4 + kt) * 64 + lane) * 8);

  // P5: per-channel softmax over 17 neighbors + weighted mean of (v_j + delta) -> opre f16 in PH
  {
    int r0 = pp5 * KP1;
    const char* abase = smem + ATT_OFF + c5 * ATT_RB + pp5 * 40;
    h4 t0 = *(const h4*)(abase + 0);
    h4 t1 = *(const h4*)(abase + 8);
    h4 t2 = *(const h4*)(abase + 16);
    h4 t3 = *(const h4*)(abase + 24);
    float att[KP1];
#pragma unroll
    for (int q = 0; q < 4; ++q) {
      att[0 + q]  = (float)t0[q];
      att[4 + q]  = (float)t1[q];
      att[8 + q]  = (float)t2[q];
      att[12 + q] = (float)t3[q];
    }
    att[16] = (float)*(const _Float16*)(abase + 32);
    // max tree (short dependency chain; max is exact so any association is identical)
    float m8[8];
#pragma unroll
    for (int k = 0; k < 8; ++k) m8[k] = fmaxf(att[k], att[k + 8]);
    float m4a = fmaxf(m8[0], m8[1]), m4b = fmaxf(m8[2], m8[3]);
    float m4c = fmaxf(m8[4], m8[5]), m4d = fmaxf(m8[6], m8[7]);
    float m = fmaxf(fmaxf(fmaxf(m4a, m4b), fmaxf(m4c, m4d)), att[16]);
    float den = 0.f;
#pragma unroll
    for (int k = 0; k < KP1; ++k) { att[k] = __expf(att[k] - m); den += att[k]; }
    float inv = 1.f / (den * 17.f);
    float acc = 0.f;
#pragma unroll
    for (int k = 0; k < KP1; ++k) {
      float dd = (float)*(const _Float16*)(smem + DELTA_OFF + swzB(r0 + k, c5 * 2));
      acc += att[k] * (vreg[k] + dd);
    }
    // opre row pp5 (0..3), col c5 -> f16 (RTN) into dead PH region, swzB layout
    *(_Float16*)(smem + PH_OFF + swzB(pp5, c5 * 2)) = (_Float16)(acc * inv);
  }
  __syncthreads();

  // P6: out = relu(opre @ Wo + bo). One 16-row M-tile; rows 0..3 real, 4..15 stale-but-finite.
  {
    fx4 acc = {0.f, 0.f, 0.f, 0.f};
#pragma unroll
    for (int kt = 0; kt < 4; ++kt) {
      h8 a = *(const h8*)(smem + PH_OFF + swzB(rl, kt * 64 + kl * 16));
      acc = __builtin_amdgcn_mfma_f32_16x16x32_f16(a, bw[kt], acc, 0, 0, 0);
    }
    if (kl == 0) {               // acc rows 0..3 = the block's 4 points
      int col = wid * 16 + rl;
      float bov = bo[col];
#pragma unroll
      for (int jj = 0; jj < 4; ++jj)
        out[(size_t)(p0 + jj) * 128 + col] = fmaxf(acc[jj] + bov, 0.f);
    }
  }
}

extern "C" void kernel_launch(void* const* d_in, const int* in_sizes, int n_in,
                              void* d_out, int out_size, void* d_ws, size_t ws_size,
                              hipStream_t stream) {
  const float* x    = (const float*)d_in[0];
  const float* pos  = (const float*)d_in[1];
  const float* Wi   = (const float*)d_in[3];
  const float* bi   = (const float*)d_in[4];
  const float* Wsrc = (const float*)d_in[5];
  const float* Wdst = (const float*)d_in[6];
  const float* Wlin = (const float*)d_in[7];
  const float* Wp1  = (const float*)d_in[8];
  const float* bp1  = (const float*)d_in[9];
  const float* Wp2  = (const float*)d_in[10];
  const float* bp2  = (const float*)d_in[11];
  const float* Wa1  = (const float*)d_in[12];
  const float* ba1  = (const float*)d_in[13];
  const float* Wa2  = (const float*)d_in[14];
  const float* ba2  = (const float*)d_in[15];
  const float* Wo   = (const float*)d_in[16];
  const float* bo   = (const float*)d_in[17];
  float* out = (float*)d_out;

  char* ws = (char*)d_ws;
  float* h    = (float*)(ws + 0);          // 16384x64   (4 MB)
  float* usv  = (float*)(ws + 4194304);    // 16384x256  (16 MB): [u|s|v]
  float* Wall = (float*)(ws + 20971520);   // 64x256 (64 KB)
  float* rel  = (float*)(ws + 21037056);   // 16384x17x3 f32 (3.34 MB)
  int*   nbr  = (int*)  (ws + 29360128);   // 16384x17
  _Float16* p2p = (_Float16*)(ws + 30474240);  // 16 KB
  _Float16* a1p = (_Float16*)(ws + 30490624);
  _Float16* a2p = (_Float16*)(ws + 30507008);
  _Float16* wop = (_Float16*)(ws + 30523392);  // 32 KB (Wo packed)

  phase1_kernel<<<P1_GRID, 512, 0, stream>>>(x, Wi, bi, h, Wdst, Wsrc, Wlin, Wa1, Wall);
  knn_usv_kernel<<<K2_GRID, 512, 0, stream>>>(pos, nbr, rel, h, Wall, usv,
                                              Wp2, Wa1, Wa2, Wo, p2p, a1p, a2p, wop);
  edge_kernel<<<4096, 512, 0, stream>>>(nbr, usv, rel, Wp1, bp1, bp2, ba1, ba2,
                                        p2p, a1p, a2p, wop, bo, out);
}